// Round 8
// baseline (362.420 us; speedup 1.0000x reference)
//
#include <hip/hip_runtime.h>
#include <hip/hip_bf16.h>
#include <cstdint>

using i32x4 = __attribute__((ext_vector_type(4))) int;

// Problem dims
#define BATCH   128
#define NPATCH  196
#define MTOT    25088   // 128*196, = 98*256 exactly
#define MT      98      // M-tiles of 256
#define DDIM    768
#define WCON    32
#define NCOLS   4096    // BATCH*WCON
#define BNC     128     // cols per chunk
#define NBN     32      // NCOLS/BNC
#define NT      12      // K-tiles of 64
#define NCHUNK  3136    // MT*NBN
#define NPBLK   512     // persistent blocks (2/CU)

// ws layout (bytes), each 256-aligned
#define PI8_OFF   0ull
#define PI8_BYTES ((size_t)MTOT*DDIM)
#define CI8_OFF   (PI8_OFF + PI8_BYTES)
#define CI8_BYTES (4096ull*DDIM)
#define SP_OFF    (CI8_OFF + CI8_BYTES)
#define SP_BYTES  ((size_t)MTOT*4)
#define SC_OFF    (SP_OFF + SP_BYTES)
#define SC_BYTES  (4096ull*4)
#define IMGN_OFF  (SC_OFF + SC_BYTES)
#define F_BYTES   (128ull*768*4)
#define TXTN_OFF  (IMGN_OFF + F_BYTES)
#define MAX_OFF   (TXTN_OFF + F_BYTES)
#define MAX_BYTES (128ull*4096*4)
#define ACC_OFF   (MAX_OFF + MAX_BYTES)
#define WS_NEED   (ACC_OFF + 256ull)

__device__ __forceinline__ void async_cp16(void* lds_p, const void* g) {
  __builtin_amdgcn_global_load_lds(
      (const __attribute__((address_space(1))) unsigned int*)g,
      (__attribute__((address_space(3))) unsigned int*)lds_p, 16, 0, 0);
}

__device__ __forceinline__ float neg_log_sigmoid(float x) {
  return (x > 0.f) ? log1pf(expf(-x)) : (log1pf(expf(x)) - x);
}

__device__ __forceinline__ int encf(float f) {
  int i = __float_as_int(f);
  return i >= 0 ? i : (i ^ 0x7FFFFFFF);
}
__device__ __forceinline__ float decf(int e) {
  return __int_as_float(e >= 0 ? e : (e ^ 0x7FFFFFFF));
}

template<int VM>
__device__ __forceinline__ void vmwait() {
  asm volatile("s_waitcnt vmcnt(%0)" :: "n"(VM) : "memory");
}
__device__ __forceinline__ void blockbar() {
  asm volatile("" ::: "memory");
  __builtin_amdgcn_s_barrier();
  asm volatile("" ::: "memory");
}

// ---------------- normalization kernels ----------------

// rows 0..127: image_features -> imgn ; rows 128..255: text_features -> txtn
__global__ void norm_f32_kernel(const float* __restrict__ ina, const float* __restrict__ inb,
                                float* __restrict__ outa, float* __restrict__ outb) {
  int row = blockIdx.x;
  int t = threadIdx.x; // 0..191
  const float* in = (row < BATCH) ? ina + (size_t)row * DDIM : inb + (size_t)(row - BATCH) * DDIM;
  float* out = (row < BATCH) ? outa + (size_t)row * DDIM : outb + (size_t)(row - BATCH) * DDIM;
  float4 v = ((const float4*)in)[t];
  float ss = v.x*v.x + v.y*v.y + v.z*v.z + v.w*v.w;
  __shared__ float sb[3];
  #pragma unroll
  for (int o = 32; o; o >>= 1) ss += __shfl_down(ss, o);
  if ((t & 63) == 0) sb[t >> 6] = ss;
  __syncthreads();
  float tot = sb[0] + sb[1] + sb[2];
  float scale = 1.0f / fmaxf(sqrtf(tot), 1e-12f);
  ((float4*)out)[t] = make_float4(v.x*scale, v.y*scale, v.z*scale, v.w*scale);
}

// per-row: normalize + symmetric-absmax int8 quantization.
__global__ void norm_quant_i8(const float* __restrict__ in, char* __restrict__ out,
                              float* __restrict__ srow) {
  int row = blockIdx.x;
  int t = threadIdx.x; // 0..191
  const float4* ir = (const float4*)(in + (size_t)row * DDIM);
  float4 v = ir[t];
  float ss = v.x*v.x + v.y*v.y + v.z*v.z + v.w*v.w;
  float am = fmaxf(fmaxf(fabsf(v.x), fabsf(v.y)), fmaxf(fabsf(v.z), fabsf(v.w)));
  __shared__ float sbs[3], sba[3];
  #pragma unroll
  for (int o = 32; o; o >>= 1) {
    ss += __shfl_down(ss, o);
    am = fmaxf(am, __shfl_down(am, o));
  }
  if ((t & 63) == 0) { sbs[t >> 6] = ss; sba[t >> 6] = am; }
  __syncthreads();
  float tot = sbs[0] + sbs[1] + sbs[2];
  float amx = fmaxf(fmaxf(sba[0], sba[1]), fmaxf(sba[2], 1e-30f));
  float qs = 127.0f / amx;
  int qx = (int)rintf(v.x * qs), qy = (int)rintf(v.y * qs);
  int qz = (int)rintf(v.z * qs), qw = (int)rintf(v.w * qs);
  uint packed = (uint)(qx & 0xff) | ((uint)(qy & 0xff) << 8) |
                ((uint)(qz & 0xff) << 16) | ((uint)(qw & 0xff) << 24);
  ((uint*)(out + (size_t)row * DDIM))[t] = packed;
  if (t == 0) srow[row] = amx / (127.0f * fmaxf(sqrtf(tot), 1e-12f));
}

// ---------------- persistent RC GEMM (int8) + column max ----------------
// 512 persistent blocks, dynamic chunk counter (work stealing). Chunk =
// 256 rows x 128 cols, 12 K-tiles of 64. 256 threads, 4 waves (2Mx2N),
// wave 128x64. 3 LDS buffers x 24KB, quad-XOR swizzle. R6 tile body:
// {stage(t+2) | vmcnt(6) | bar | READS(t+1)+MFMA(t) | bar}. Pipeline never
// drains across chunks. ALL chunk state scalarized via readfirstlane.
__global__ __launch_bounds__(256, 2)
void rc_gemm_max_kernel(const char* __restrict__ patches,
                        const char* __restrict__ concepts,
                        const float* __restrict__ sp,
                        const float* __restrict__ sc,
                        int* __restrict__ ctr,
                        int* __restrict__ Max) {
  __shared__ __align__(16) char lds[3 * 24576];
  __shared__ float sp_lds[256];
  __shared__ float colmax[2][2][128];
  __shared__ int chunk_lds[2];

  const int tid = threadIdx.x;
  const int lane = tid & 63;
  const int wid = tid >> 6;
  const int wm = wid >> 1;   // 0..1
  const int wn = wid & 1;    // 0..1

  // ds_read base offsets (quad-XOR swizzle; slot invariant across frag idx)
  const int arow = wm*128 + (lane & 15);
  const int aslot = (lane >> 4) ^ (((lane & 15) >> 1) & 3);
  const int a_base = arow*64 + aslot*16;
  const int bcl = wn*64 + (lane & 15);
  const int b_base = 16384 + bcl*64 + aslot*16;
  // staging voffset (element==byte for i8); slot invariant across k2 chunks
  const int r0 = tid >> 2;
  const int q0 = (tid & 3) ^ ((r0 >> 1) & 3);
  const int svoff = r0*DDIM + q0*16;

  i32x4 acc[8][4];
  #pragma unroll
  for (int i = 0; i < 8; ++i)
    #pragma unroll
    for (int j = 0; j < 4; ++j) { i32x4 z = {0,0,0,0}; acc[i][j] = z; }

  i32x4 a0[8], b0[4], a1[8], b1[4];   // fragment double-buffer

  if (tid == 0) {
    chunk_lds[0] = atomicAdd(ctr, 1);
    chunk_lds[1] = atomicAdd(ctr, 1);
  }
  __syncthreads();
  int cur = __builtin_amdgcn_readfirstlane(chunk_lds[0]);
  int nxt = __builtin_amdgcn_readfirstlane(chunk_lds[1]);
  if (cur >= NCHUNK) return;

  // scalar chunk state
  int cbn = cur / MT, cmt = cur - cbn * MT;
  const char* curA = patches  + (size_t)cmt * 256 * DDIM;
  const char* curB = concepts + (size_t)cbn * BNC * DDIM;
  int brow = cmt * 256, bcol = cbn * BNC;
  sp_lds[tid] = sp[brow + tid];

  auto stage = [&](const char* A, const char* B, int kcol, int bufi) {
    char* dst = lds + bufi * 24576;
    #pragma unroll
    for (int k2 = 0; k2 < 4; ++k2)
      async_cp16(dst + tid*16 + k2*4096, A + svoff + k2*(64*DDIM) + kcol);
    #pragma unroll
    for (int k2 = 0; k2 < 2; ++k2)
      async_cp16(dst + 16384 + tid*16 + k2*4096, B + svoff + k2*(64*DDIM) + kcol);
  };

#define READS(AF, BF, BUFI)                                                   \
  {                                                                           \
    const char* _p = lds + (BUFI) * 24576;                                    \
    _Pragma("unroll")                                                         \
    for (int _i = 0; _i < 8; ++_i)                                            \
      AF[_i] = *(const i32x4*)(_p + a_base + _i*1024);                        \
    _Pragma("unroll")                                                         \
    for (int _j = 0; _j < 4; ++_j)                                            \
      BF[_j] = *(const i32x4*)(_p + b_base + _j*1024);                        \
  }

#define MFMA32(AF, BF)                                                        \
  {                                                                           \
    __builtin_amdgcn_s_setprio(1);                                            \
    _Pragma("unroll")                                                         \
    for (int _i = 0; _i < 8; ++_i)                                            \
      _Pragma("unroll")                                                       \
      for (int _j = 0; _j < 4; ++_j)                                          \
        acc[_i][_j] = __builtin_amdgcn_mfma_i32_16x16x64_i8(AF[_i], BF[_j],   \
                                                            acc[_i][_j], 0,0,0); \
    __builtin_amdgcn_s_setprio(0);                                            \
  }

#define BODY(T, AC, BC, AR, BR)                                               \
  {                                                                           \
    stage(curA, curB, ((T)+2)*64, ((T)+2)%3);                                 \
    vmwait<6>();                                                              \
    blockbar();                                                               \
    READS(AR, BR, ((T)+1)%3)                                                  \
    MFMA32(AC, BC)                                                            \
    blockbar();                                                               \
  }

  // prologue: stage cur tiles 0,1; read frags(0) into set0
  stage(curA, curB, 0, 0);
  stage(curA, curB, 64, 1);
  vmwait<6>();
  blockbar();
  READS(a0, b0, 0)

  for (;;) {
    const bool have_next = (nxt < NCHUNK);
    int nbn = 0, nmt = 0;
    const char *nA = curA, *nB = curB;
    if (have_next) {
      nbn = nxt / MT; nmt = nxt - nbn * MT;     // scalar math (nxt is SGPR)
      nA = patches  + (size_t)nmt * 256 * DDIM;
      nB = concepts + (size_t)nbn * BNC * DDIM;
    }
    if (tid == 0) chunk_lds[0] = have_next ? atomicAdd(ctr, 1) : NCHUNK;

    BODY(0, a0,b0, a1,b1)  BODY(1, a1,b1, a0,b0)
    BODY(2, a0,b0, a1,b1)  BODY(3, a1,b1, a0,b0)
    BODY(4, a0,b0, a1,b1)  BODY(5, a1,b1, a0,b0)
    BODY(6, a0,b0, a1,b1)  BODY(7, a1,b1, a0,b0)
    BODY(8, a0,b0, a1,b1)  BODY(9, a1,b1, a0,b0)

    if (have_next) {
      // t=10: stage next tile 0 -> buf0 ; t=11: stage next tile 1 -> buf1
      { stage(nA, nB, 0, 0); vmwait<6>(); blockbar();
        READS(a1, b1, 2) MFMA32(a0, b0) blockbar(); }
      { stage(nA, nB, 64, 1); vmwait<6>(); blockbar();
        READS(a0, b0, 0) MFMA32(a1, b1) blockbar(); }
    } else {
      { vmwait<0>(); blockbar();
        READS(a1, b1, 2) MFMA32(a0, b0) blockbar(); }
      { blockbar();
        MFMA32(a1, b1) blockbar(); }
    }

    // ---- epilogue for cur: dequant + segmented column max ----
    {
      float cmax[4][2];
      #pragma unroll
      for (int j = 0; j < 4; ++j) { cmax[j][0] = -3e38f; cmax[j][1] = -3e38f; }
      float scv[4];
      #pragma unroll
      for (int j = 0; j < 4; ++j) scv[j] = sc[bcol + wn*64 + j*16 + (lane & 15)];
      const int img0w = (brow + wm*128) / NPATCH;
      #pragma unroll
      for (int i = 0; i < 8; ++i) {
        #pragma unroll
        for (int e = 0; e < 4; ++e) {
          int rl = wm*128 + i*16 + (lane >> 4)*4 + e;
          float spv = sp_lds[rl];
          int seg = ((brow + rl) / NPATCH) - img0w;   // 0 or 1
          #pragma unroll
          for (int j = 0; j < 4; ++j) {
            float v = (float)acc[i][j][e] * spv * scv[j];
            cmax[j][0] = (seg == 0) ? fmaxf(cmax[j][0], v) : cmax[j][0];
            cmax[j][1] = (seg == 1) ? fmaxf(cmax[j][1], v) : cmax[j][1];
          }
        }
      }
      #pragma unroll
      for (int j = 0; j < 4; ++j) {
        #pragma unroll
        for (int s = 0; s < 2; ++s) {
          float v = cmax[j][s];
          v = fmaxf(v, __shfl_xor(v, 16));
          v = fmaxf(v, __shfl_xor(v, 32));
          cmax[j][s] = v;
        }
      }
      if (lane < 16) {
        #pragma unroll
        for (int j = 0; j < 4; ++j) {
          colmax[wm][0][wn*64 + j*16 + lane] = cmax[j][0];
          colmax[wm][1][wn*64 + j*16 + lane] = cmax[j][1];
        }
      }
      __syncthreads();
      {
        int w = tid >> 7;
        int col = tid & 127;
        int i0 = (brow + w*128) / NPATCH;
        int i1 = (brow + w*128 + 127) / NPATCH;
        int gcol = bcol + col;
        atomicMax(&Max[(size_t)i0 * NCOLS + gcol], encf(colmax[w][0][col]));
        if (i1 != i0) atomicMax(&Max[(size_t)i1 * NCOLS + gcol], encf(colmax[w][1][col]));
      }
      #pragma unroll
      for (int i = 0; i < 8; ++i)
        #pragma unroll
        for (int j = 0; j < 4; ++j) { i32x4 z = {0,0,0,0}; acc[i][j] = z; }
    }

    if (!have_next) return;
    __syncthreads();            // colmax/epilogue done; chunk_lds stable
    cur = nxt; curA = nA; curB = nB; brow = nmt * 256; bcol = nbn * BNC;
    nxt = __builtin_amdgcn_readfirstlane(chunk_lds[0]);
    __syncthreads();            // all read chunk_lds before next top write
    sp_lds[tid] = sp[brow + tid];
  }
#undef BODY
#undef MFMA32
#undef READS
}

// ---------------- losses ----------------

__global__ void it_loss_kernel(const float* __restrict__ imgn, const float* __restrict__ txtn,
                               const float* __restrict__ sc, const float* __restrict__ bi,
                               float* __restrict__ acc) {
  int m = blockIdx.x;
  int c = threadIdx.x;  // 128 threads
  __shared__ __align__(16) float arow[DDIM];
  for (int k = c; k < DDIM; k += 128) arow[k] = imgn[(size_t)m * DDIM + k];
  __syncthreads();
  const float4* br = (const float4*)(txtn + (size_t)c * DDIM);
  const float4* ar = (const float4*)arow;
  float dot = 0.f;
  #pragma unroll 8
  for (int k = 0; k < DDIM/4; ++k) {
    float4 x = ar[k], y = br[k];
    dot += x.x*y.x + x.y*y.y + x.z*y.z + x.w*y.w;
  }
  float t = expf(fminf(fmaxf(sc[0], -10.f), 10.f));
  float logit = fminf(fmaxf(t*dot + bi[0], -50.f), 50.f);
  float x = (c == m) ? logit : -logit;
  float v = neg_log_sigmoid(x);
  __shared__ float sb[2];
  #pragma unroll
  for (int o = 32; o; o >>= 1) v += __shfl_down(v, o);
  if ((c & 63) == 0) sb[c >> 6] = v;
  __syncthreads();
  if (c == 0) atomicAdd(acc, sb[0] + sb[1]);
}

__global__ void rc_loss_kernel(const int* __restrict__ Max, const int* __restrict__ counts,
                               const float* __restrict__ sc, const float* __restrict__ bi,
                               float* __restrict__ acc) {
  int m = blockIdx.x;
  int v = threadIdx.x;  // 128 threads
  const int* row = Max + (size_t)m * NCOLS + (size_t)v * WCON;
  int cnt = counts[v];
  float s = 0.f;
  for (int w = 0; w < cnt; ++w) s += decf(row[w]);
  float S = s / (float)cnt;
  float t = expf(fminf(fmaxf(sc[0], -10.f), 10.f));
  float logit = fminf(fmaxf(t*S + bi[0], -50.f), 50.f);
  float x = (v == m) ? logit : -logit;
  float val = neg_log_sigmoid(x);
  __shared__ float sb[2];
  #pragma unroll
  for (int o = 32; o; o >>= 1) val += __shfl_down(val, o);
  if ((v & 63) == 0) sb[v >> 6] = val;
  __syncthreads();
  if (v == 0) atomicAdd(acc, sb[0] + sb[1]);
}

__global__ void finalize_kernel(const float* __restrict__ acc, float* __restrict__ out) {
  if (threadIdx.x == 0 && blockIdx.x == 0) {
    float it = acc[0] * (1.f / 16384.f);
    float rc = acc[1] * (1.f / 16384.f);
    out[0] = it + 0.5f * rc;
    out[1] = it;
    out[2] = rc;
  }
}

// ---------------- launch ----------------

extern "C" void kernel_launch(void* const* d_in, const int* in_sizes, int n_in,
                              void* d_out, int out_size, void* d_ws, size_t ws_size,
                              hipStream_t stream) {
  const float* image_features        = (const float*)d_in[0];
  const float* text_features         = (const float*)d_in[1];
  const float* image_token_features  = (const float*)d_in[2];
  const float* concept_text_features = (const float*)d_in[3];
  const int*   concept_counts        = (const int*)d_in[4];
  const float* logit_scale           = (const float*)d_in[5];
  const float* logit_bias            = (const float*)d_in[6];
  float* out = (float*)d_out;

  if (ws_size < WS_NEED) {
    hipMemsetAsync(d_out, 0, (size_t)out_size * sizeof(float), stream);
    return;
  }

  char* ws = (char*)d_ws;
  char*  patches_i8  = ws + PI8_OFF;
  char*  concepts_i8 = ws + CI8_OFF;
  float* sp          = (float*)(ws + SP_OFF);
  float* scq         = (float*)(ws + SC_OFF);
  float* imgn        = (float*)(ws + IMGN_OFF);
  float* txtn        = (float*)(ws + TXTN_OFF);
  int*   Maxbuf      = (int*)(ws + MAX_OFF);
  float* acc         = (float*)(ws + ACC_OFF);          // [0]=it, [1]=rc
  int*   ctr         = (int*)(ws + ACC_OFF + 64);

  hipMemsetAsync(ws + ACC_OFF, 0, 256, stream);         // zero acc + ctr
  hipMemsetAsync(Maxbuf, 0x80, MAX_BYTES, stream);      // decodes very negative

  norm_f32_kernel<<<2*BATCH, 192, 0, stream>>>(image_features, text_features, imgn, txtn);
  norm_quant_i8<<<MTOT, 192, 0, stream>>>(image_token_features, patches_i8, sp);
  norm_quant_i8<<<NCOLS, 192, 0, stream>>>(concept_text_features, concepts_i8, scq);

  rc_gemm_max_kernel<<<NPBLK, 256, 0, stream>>>(patches_i8, concepts_i8, sp, scq, ctr, Maxbuf);

  it_loss_kernel<<<BATCH, 128, 0, stream>>>(imgn, txtn, logit_scale, logit_bias, acc);
  rc_loss_kernel<<<BATCH, 128, 0, stream>>>(Maxbuf, concept_counts, logit_scale, logit_bias, acc + 1);
  finalize_kernel<<<1, 64, 0, stream>>>(acc, out);
}

// Round 9
// 275.612 us; speedup vs baseline: 1.3150x; 1.3150x over previous
//
#include <hip/hip_runtime.h>
#include <hip/hip_bf16.h>
#include <cstdint>

using i32x4 = __attribute__((ext_vector_type(4))) int;

// Problem dims
#define BATCH   128
#define NPATCH  196
#define MTOT    25088   // 128*196, = 98*256 exactly
#define MT      98      // M-tiles of 256
#define DDIM    768
#define WCON    32
#define NCOLS   4096    // BATCH*WCON
#define BNC     128     // cols per chunk
#define NBN     32      // NCOLS/BNC
#define NT      12      // K-tiles of 64
#define NCHUNK  3136    // MT*NBN
#define NPBLK   512     // persistent blocks (2/CU)

// ws layout (bytes), each 256-aligned
#define PI8_OFF   0ull
#define PI8_BYTES ((size_t)MTOT*DDIM)
#define CI8_OFF   (PI8_OFF + PI8_BYTES)
#define CI8_BYTES (4096ull*DDIM)
#define SP_OFF    (CI8_OFF + CI8_BYTES)
#define SP_BYTES  ((size_t)MTOT*4)
#define SC_OFF    (SP_OFF + SP_BYTES)
#define SC_BYTES  (4096ull*4)
#define IMGN_OFF  (SC_OFF + SC_BYTES)
#define F_BYTES   (128ull*768*4)
#define TXTN_OFF  (IMGN_OFF + F_BYTES)
#define MAX_OFF   (TXTN_OFF + F_BYTES)
#define MAX_BYTES (128ull*4096*4)
#define ACC_OFF   (MAX_OFF + MAX_BYTES)
#define WS_NEED   (ACC_OFF + 256ull)

__device__ __forceinline__ void async_cp16(void* lds_p, const void* g) {
  __builtin_amdgcn_global_load_lds(
      (const __attribute__((address_space(1))) unsigned int*)g,
      (__attribute__((address_space(3))) unsigned int*)lds_p, 16, 0, 0);
}

__device__ __forceinline__ float neg_log_sigmoid(float x) {
  return (x > 0.f) ? log1pf(expf(-x)) : (log1pf(expf(x)) - x);
}

__device__ __forceinline__ int encf(float f) {
  int i = __float_as_int(f);
  return i >= 0 ? i : (i ^ 0x7FFFFFFF);
}
__device__ __forceinline__ float decf(int e) {
  return __int_as_float(e >= 0 ? e : (e ^ 0x7FFFFFFF));
}

template<int VM>
__device__ __forceinline__ void vmwait() {
  asm volatile("s_waitcnt vmcnt(%0)" :: "n"(VM) : "memory");
}
__device__ __forceinline__ void blockbar() {
  asm volatile("" ::: "memory");
  __builtin_amdgcn_s_barrier();
  asm volatile("" ::: "memory");
}

// ---------------- normalization kernels ----------------

// rows 0..127: image_features -> imgn ; rows 128..255: text_features -> txtn
__global__ void norm_f32_kernel(const float* __restrict__ ina, const float* __restrict__ inb,
                                float* __restrict__ outa, float* __restrict__ outb) {
  int row = blockIdx.x;
  int t = threadIdx.x; // 0..191
  const float* in = (row < BATCH) ? ina + (size_t)row * DDIM : inb + (size_t)(row - BATCH) * DDIM;
  float* out = (row < BATCH) ? outa + (size_t)row * DDIM : outb + (size_t)(row - BATCH) * DDIM;
  float4 v = ((const float4*)in)[t];
  float ss = v.x*v.x + v.y*v.y + v.z*v.z + v.w*v.w;
  __shared__ float sb[3];
  #pragma unroll
  for (int o = 32; o; o >>= 1) ss += __shfl_down(ss, o);
  if ((t & 63) == 0) sb[t >> 6] = ss;
  __syncthreads();
  float tot = sb[0] + sb[1] + sb[2];
  float scale = 1.0f / fmaxf(sqrtf(tot), 1e-12f);
  ((float4*)out)[t] = make_float4(v.x*scale, v.y*scale, v.z*scale, v.w*scale);
}

// per-row: normalize + symmetric-absmax int8 quantization.
__global__ void norm_quant_i8(const float* __restrict__ in, char* __restrict__ out,
                              float* __restrict__ srow) {
  int row = blockIdx.x;
  int t = threadIdx.x; // 0..191
  const float4* ir = (const float4*)(in + (size_t)row * DDIM);
  float4 v = ir[t];
  float ss = v.x*v.x + v.y*v.y + v.z*v.z + v.w*v.w;
  float am = fmaxf(fmaxf(fabsf(v.x), fabsf(v.y)), fmaxf(fabsf(v.z), fabsf(v.w)));
  __shared__ float sbs[3], sba[3];
  #pragma unroll
  for (int o = 32; o; o >>= 1) {
    ss += __shfl_down(ss, o);
    am = fmaxf(am, __shfl_down(am, o));
  }
  if ((t & 63) == 0) { sbs[t >> 6] = ss; sba[t >> 6] = am; }
  __syncthreads();
  float tot = sbs[0] + sbs[1] + sbs[2];
  float amx = fmaxf(fmaxf(sba[0], sba[1]), fmaxf(sba[2], 1e-30f));
  float qs = 127.0f / amx;
  int qx = (int)rintf(v.x * qs), qy = (int)rintf(v.y * qs);
  int qz = (int)rintf(v.z * qs), qw = (int)rintf(v.w * qs);
  uint packed = (uint)(qx & 0xff) | ((uint)(qy & 0xff) << 8) |
                ((uint)(qz & 0xff) << 16) | ((uint)(qw & 0xff) << 24);
  ((uint*)(out + (size_t)row * DDIM))[t] = packed;
  if (t == 0) srow[row] = amx / (127.0f * fmaxf(sqrtf(tot), 1e-12f));
}

// ---------------- persistent RC GEMM (int8) + column max ----------------
// 512 persistent blocks, dynamic chunk counter. Chunk = 256x128, 12 K-tiles
// of 64. 256 threads, 4 waves (2Mx2N), wave 128x64. 3 LDS bufs x 24KB,
// quad-XOR swizzle. R6 tile body (single frag set, spill-free):
// {stage(t+2) | vmcnt(6) | bar | reads+MFMA(t) | bar}. Bodies 10/11 stage
// next chunk's tiles 0/1 -> pipeline never drains across chunks.
__global__ __launch_bounds__(256, 2)
void rc_gemm_max_kernel(const char* __restrict__ patches,
                        const char* __restrict__ concepts,
                        const float* __restrict__ sp,
                        const float* __restrict__ sc,
                        int* __restrict__ ctr,
                        int* __restrict__ Max) {
  __shared__ __align__(16) char lds[3 * 24576];
  __shared__ float sp_lds[256];
  __shared__ float colmax[2][2][128];
  __shared__ int chunk_lds[2];

  const int tid = threadIdx.x;
  const int lane = tid & 63;
  const int wid = tid >> 6;
  const int wm = wid >> 1;   // 0..1
  const int wn = wid & 1;    // 0..1

  // ds_read base offsets (quad-XOR swizzle; slot invariant across frag idx)
  const int arow = wm*128 + (lane & 15);
  const int aslot = (lane >> 4) ^ (((lane & 15) >> 1) & 3);
  const int a_base = arow*64 + aslot*16;
  const int bcl = wn*64 + (lane & 15);
  const int b_base = 16384 + bcl*64 + aslot*16;
  // staging voffset (element==byte for i8); slot invariant across k2 chunks
  const int r0 = tid >> 2;
  const int q0 = (tid & 3) ^ ((r0 >> 1) & 3);
  const int svoff = r0*DDIM + q0*16;

  i32x4 acc[8][4];
  #pragma unroll
  for (int i = 0; i < 8; ++i)
    #pragma unroll
    for (int j = 0; j < 4; ++j) { i32x4 z = {0,0,0,0}; acc[i][j] = z; }

  if (tid == 0) {
    chunk_lds[0] = atomicAdd(ctr, 1);
    chunk_lds[1] = atomicAdd(ctr, 1);
  }
  __syncthreads();
  int cur = __builtin_amdgcn_readfirstlane(chunk_lds[0]);
  int nxt = __builtin_amdgcn_readfirstlane(chunk_lds[1]);
  if (cur >= NCHUNK) return;

  // scalar chunk state
  int cbn = cur / MT, cmt = cur - cbn * MT;
  const char* curA = patches  + (size_t)cmt * 256 * DDIM;
  const char* curB = concepts + (size_t)cbn * BNC * DDIM;
  int brow = cmt * 256, bcol = cbn * BNC;
  sp_lds[tid] = sp[brow + tid];

  auto stage = [&](const char* A, const char* B, int kcol, int bufi) {
    char* dst = lds + bufi * 24576;
    #pragma unroll
    for (int k2 = 0; k2 < 4; ++k2)
      async_cp16(dst + tid*16 + k2*4096, A + svoff + k2*(64*DDIM) + kcol);
    #pragma unroll
    for (int k2 = 0; k2 < 2; ++k2)
      async_cp16(dst + 16384 + tid*16 + k2*4096, B + svoff + k2*(64*DDIM) + kcol);
  };

  // single-frag-set compute (R6 form — fits the register budget, no spill)
  auto compute = [&](int bufi) {
    const char* ab = lds + bufi * 24576;
    i32x4 a[8], b[4];
    #pragma unroll
    for (int i = 0; i < 8; ++i) a[i] = *(const i32x4*)(ab + a_base + i*1024);
    #pragma unroll
    for (int j = 0; j < 4; ++j) b[j] = *(const i32x4*)(ab + b_base + j*1024);
    __builtin_amdgcn_s_setprio(1);
    #pragma unroll
    for (int i = 0; i < 8; ++i)
      #pragma unroll
      for (int j = 0; j < 4; ++j)
        acc[i][j] = __builtin_amdgcn_mfma_i32_16x16x64_i8(a[i], b[j], acc[i][j], 0, 0, 0);
    __builtin_amdgcn_s_setprio(0);
  };

#define BODY(T)                                                               \
  {                                                                           \
    stage(curA, curB, ((T)+2)*64, ((T)+2)%3);                                 \
    vmwait<6>();                                                              \
    blockbar();                                                               \
    compute((T)%3);                                                           \
    blockbar();                                                               \
  }

  // prologue: stage cur tiles 0,1
  stage(curA, curB, 0, 0);
  stage(curA, curB, 64, 1);

  for (;;) {
    const bool have_next = (nxt < NCHUNK);
    int nbn = 0, nmt = 0;
    const char *nA = curA, *nB = curB;
    if (have_next) {
      nbn = nxt / MT; nmt = nxt - nbn * MT;     // scalar math (nxt is SGPR)
      nA = patches  + (size_t)nmt * 256 * DDIM;
      nB = concepts + (size_t)nbn * BNC * DDIM;
    }
    if (tid == 0) chunk_lds[0] = have_next ? atomicAdd(ctr, 1) : NCHUNK;

    BODY(0) BODY(1) BODY(2) BODY(3) BODY(4)
    BODY(5) BODY(6) BODY(7) BODY(8) BODY(9)

    if (have_next) {
      // body 10/11: stage next chunk tiles 0,1 (12 % 3 == 0 -> bufs 0,1)
      { stage(nA, nB, 0, 0);  vmwait<6>(); blockbar(); compute(1); blockbar(); }
      { stage(nA, nB, 64, 1); vmwait<6>(); blockbar(); compute(2); blockbar(); }
    } else {
      { vmwait<0>(); blockbar(); compute(1); blockbar(); }
      { blockbar(); compute(2); blockbar(); }
    }

    // ---- epilogue for cur: dequant + segmented column max ----
    {
      float cmax[4][2];
      #pragma unroll
      for (int j = 0; j < 4; ++j) { cmax[j][0] = -3e38f; cmax[j][1] = -3e38f; }
      float scv[4];
      #pragma unroll
      for (int j = 0; j < 4; ++j) scv[j] = sc[bcol + wn*64 + j*16 + (lane & 15)];
      const int img0w = (brow + wm*128) / NPATCH;
      #pragma unroll
      for (int i = 0; i < 8; ++i) {
        #pragma unroll
        for (int e = 0; e < 4; ++e) {
          int rl = wm*128 + i*16 + (lane >> 4)*4 + e;
          float spv = sp_lds[rl];
          int seg = ((brow + rl) / NPATCH) - img0w;   // 0 or 1
          #pragma unroll
          for (int j = 0; j < 4; ++j) {
            float v = (float)acc[i][j][e] * spv * scv[j];
            cmax[j][0] = (seg == 0) ? fmaxf(cmax[j][0], v) : cmax[j][0];
            cmax[j][1] = (seg == 1) ? fmaxf(cmax[j][1], v) : cmax[j][1];
          }
        }
      }
      #pragma unroll
      for (int j = 0; j < 4; ++j) {
        #pragma unroll
        for (int s = 0; s < 2; ++s) {
          float v = cmax[j][s];
          v = fmaxf(v, __shfl_xor(v, 16));
          v = fmaxf(v, __shfl_xor(v, 32));
          cmax[j][s] = v;
        }
      }
      if (lane < 16) {
        #pragma unroll
        for (int j = 0; j < 4; ++j) {
          colmax[wm][0][wn*64 + j*16 + lane] = cmax[j][0];
          colmax[wm][1][wn*64 + j*16 + lane] = cmax[j][1];
        }
      }
      __syncthreads();
      {
        int w = tid >> 7;
        int col = tid & 127;
        int i0 = (brow + w*128) / NPATCH;
        int i1 = (brow + w*128 + 127) / NPATCH;
        int gcol = bcol + col;
        atomicMax(&Max[(size_t)i0 * NCOLS + gcol], encf(colmax[w][0][col]));
        if (i1 != i0) atomicMax(&Max[(size_t)i1 * NCOLS + gcol], encf(colmax[w][1][col]));
      }
      #pragma unroll
      for (int i = 0; i < 8; ++i)
        #pragma unroll
        for (int j = 0; j < 4; ++j) { i32x4 z = {0,0,0,0}; acc[i][j] = z; }
    }

    if (!have_next) return;
    __syncthreads();            // epilogue done; chunk_lds stable to read
    cur = nxt; curA = nA; curB = nB; brow = nmt * 256; bcol = nbn * BNC;
    nxt = __builtin_amdgcn_readfirstlane(chunk_lds[0]);
    __syncthreads();            // all read chunk_lds before next top write
    sp_lds[tid] = sp[brow + tid];
  }
#undef BODY
}

// ---------------- losses ----------------

__global__ void it_loss_kernel(const float* __restrict__ imgn, const float* __restrict__ txtn,
                               const float* __restrict__ sc, const float* __restrict__ bi,
                               float* __restrict__ acc) {
  int m = blockIdx.x;
  int c = threadIdx.x;  // 128 threads
  __shared__ __align__(16) float arow[DDIM];
  for (int k = c; k < DDIM; k += 128) arow[k] = imgn[(size_t)m * DDIM + k];
  __syncthreads();
  const float4* br = (const float4*)(txtn + (size_t)c * DDIM);
  const float4* ar = (const float4*)arow;
  float dot = 0.f;
  #pragma unroll 8
  for (int k = 0; k < DDIM/4; ++k) {
    float4 x = ar[k], y = br[k];
    dot += x.x*y.x + x.y*y.y + x.z*y.z + x.w*y.w;
  }
  float t = expf(fminf(fmaxf(sc[0], -10.f), 10.f));
  float logit = fminf(fmaxf(t*dot + bi[0], -50.f), 50.f);
  float x = (c == m) ? logit : -logit;
  float v = neg_log_sigmoid(x);
  __shared__ float sb[2];
  #pragma unroll
  for (int o = 32; o; o >>= 1) v += __shfl_down(v, o);
  if ((c & 63) == 0) sb[c >> 6] = v;
  __syncthreads();
  if (c == 0) atomicAdd(acc, sb[0] + sb[1]);
}

__global__ void rc_loss_kernel(const int* __restrict__ Max, const int* __restrict__ counts,
                               const float* __restrict__ sc, const float* __restrict__ bi,
                               float* __restrict__ acc) {
  int m = blockIdx.x;
  int v = threadIdx.x;  // 128 threads
  const int* row = Max + (size_t)m * NCOLS + (size_t)v * WCON;
  int cnt = counts[v];
  float s = 0.f;
  for (int w = 0; w < cnt; ++w) s += decf(row[w]);
  float S = s / (float)cnt;
  float t = expf(fminf(fmaxf(sc[0], -10.f), 10.f));
  float logit = fminf(fmaxf(t*S + bi[0], -50.f), 50.f);
  float x = (v == m) ? logit : -logit;
  float val = neg_log_sigmoid(x);
  __shared__ float sb[2];
  #pragma unroll
  for (int o = 32; o; o >>= 1) val += __shfl_down(val, o);
  if ((v & 63) == 0) sb[v >> 6] = val;
  __syncthreads();
  if (v == 0) atomicAdd(acc, sb[0] + sb[1]);
}

__global__ void finalize_kernel(const float* __restrict__ acc, float* __restrict__ out) {
  if (threadIdx.x == 0 && blockIdx.x == 0) {
    float it = acc[0] * (1.f / 16384.f);
    float rc = acc[1] * (1.f / 16384.f);
    out[0] = it + 0.5f * rc;
    out[1] = it;
    out[2] = rc;
  }
}

// ---------------- launch ----------------

extern "C" void kernel_launch(void* const* d_in, const int* in_sizes, int n_in,
                              void* d_out, int out_size, void* d_ws, size_t ws_size,
                              hipStream_t stream) {
  const float* image_features        = (const float*)d_in[0];
  const float* text_features         = (const float*)d_in[1];
  const float* image_token_features  = (const float*)d_in[2];
  const float* concept_text_features = (const float*)d_in[3];
  const int*   concept_counts        = (const int*)d_in[4];
  const float* logit_scale           = (const float*)d_in[5];
  const float* logit_bias            = (const float*)d_in[6];
  float* out = (float*)d_out;

  if (ws_size < WS_NEED) {
    hipMemsetAsync(d_out, 0, (size_t)out_size * sizeof(float), stream);
    return;
  }

  char* ws = (char*)d_ws;
  char*  patches_i8  = ws + PI8_OFF;
  char*  concepts_i8 = ws + CI8_OFF;
  float* sp          = (float*)(ws + SP_OFF);
  float* scq         = (float*)(ws + SC_OFF);
  float* imgn        = (float*)(ws + IMGN_OFF);
  float* txtn        = (float*)(ws + TXTN_OFF);
  int*   Maxbuf      = (int*)(ws + MAX_OFF);
  float* acc         = (float*)(ws + ACC_OFF);          // [0]=it, [1]=rc
  int*   ctr         = (int*)(ws + ACC_OFF + 64);

  hipMemsetAsync(ws + ACC_OFF, 0, 256, stream);         // zero acc + ctr
  hipMemsetAsync(Maxbuf, 0x80, MAX_BYTES, stream);      // decodes very negative

  norm_f32_kernel<<<2*BATCH, 192, 0, stream>>>(image_features, text_features, imgn, txtn);
  norm_quant_i8<<<MTOT, 192, 0, stream>>>(image_token_features, patches_i8, sp);
  norm_quant_i8<<<NCOLS, 192, 0, stream>>>(concept_text_features, concepts_i8, scq);

  rc_gemm_max_kernel<<<NPBLK, 256, 0, stream>>>(patches_i8, concepts_i8, sp, scq, ctr, Maxbuf);

  it_loss_kernel<<<BATCH, 128, 0, stream>>>(imgn, txtn, logit_scale, logit_bias, acc);
  rc_loss_kernel<<<BATCH, 128, 0, stream>>>(Maxbuf, concept_counts, logit_scale, logit_bias, acc + 1);
  finalize_kernel<<<1, 64, 0, stream>>>(acc, out);
}

// Round 10
// 185.172 us; speedup vs baseline: 1.9572x; 1.4884x over previous
//
#include <hip/hip_runtime.h>
#include <hip/hip_bf16.h>
#include <cstdint>

using i32x4 = __attribute__((ext_vector_type(4))) int;

// Problem dims
#define BATCH   128
#define NPATCH  196
#define MTOT    25088   // 128*196, = 98*256 exactly
#define MT      98      // M-tiles of 256
#define DDIM    768
#define WCON    32
#define NCOLS   4096    // BATCH*WCON
#define BNC     256     // cols per block
#define NBN     16      // NCOLS/BNC
#define NT      12      // K-tiles of 64
#define NBLK    1568    // MT*NBN = 8*196

// ws layout (bytes), each 256-aligned
#define PI8_OFF   0ull
#define PI8_BYTES ((size_t)MTOT*DDIM)
#define CI8_OFF   (PI8_OFF + PI8_BYTES)
#define CI8_BYTES (4096ull*DDIM)
#define SP_OFF    (CI8_OFF + CI8_BYTES)
#define SP_BYTES  ((size_t)MTOT*4)
#define SC_OFF    (SP_OFF + SP_BYTES)
#define SC_BYTES  (4096ull*4)
#define IMGN_OFF  (SC_OFF + SC_BYTES)
#define F_BYTES   (128ull*768*4)
#define TXTN_OFF  (IMGN_OFF + F_BYTES)
#define MAX_OFF   (TXTN_OFF + F_BYTES)
#define MAX_BYTES (128ull*4096*4)
#define ACC_OFF   (MAX_OFF + MAX_BYTES)
#define WS_NEED   (ACC_OFF + 256ull)

__device__ __forceinline__ void async_cp16(void* lds_p, const void* g) {
  __builtin_amdgcn_global_load_lds(
      (const __attribute__((address_space(1))) unsigned int*)g,
      (__attribute__((address_space(3))) unsigned int*)lds_p, 16, 0, 0);
}

__device__ __forceinline__ float neg_log_sigmoid(float x) {
  return (x > 0.f) ? log1pf(expf(-x)) : (log1pf(expf(x)) - x);
}

// monotone float<->int encoding for atomicMax on floats (no NaNs here)
__device__ __forceinline__ int encf(float f) {
  int i = __float_as_int(f);
  return i >= 0 ? i : (i ^ 0x7FFFFFFF);
}
__device__ __forceinline__ float decf(int e) {
  return __int_as_float(e >= 0 ? e : (e ^ 0x7FFFFFFF));
}

template<int VM>
__device__ __forceinline__ void vmwait() {
  asm volatile("s_waitcnt vmcnt(%0)" :: "n"(VM) : "memory");
}
__device__ __forceinline__ void blockbar() {
  asm volatile("" ::: "memory");
  __builtin_amdgcn_s_barrier();
  asm volatile("" ::: "memory");
}

// ---------------- normalization kernels ----------------

// rows 0..127: image_features -> imgn ; rows 128..255: text_features -> txtn
__global__ void norm_f32_kernel(const float* __restrict__ ina, const float* __restrict__ inb,
                                float* __restrict__ outa, float* __restrict__ outb) {
  int row = blockIdx.x;
  int t = threadIdx.x; // 0..191
  const float* in = (row < BATCH) ? ina + (size_t)row * DDIM : inb + (size_t)(row - BATCH) * DDIM;
  float* out = (row < BATCH) ? outa + (size_t)row * DDIM : outb + (size_t)(row - BATCH) * DDIM;
  float4 v = ((const float4*)in)[t];
  float ss = v.x*v.x + v.y*v.y + v.z*v.z + v.w*v.w;
  __shared__ float sb[3];
  #pragma unroll
  for (int o = 32; o; o >>= 1) ss += __shfl_down(ss, o);
  if ((t & 63) == 0) sb[t >> 6] = ss;
  __syncthreads();
  float tot = sb[0] + sb[1] + sb[2];
  float scale = 1.0f / fmaxf(sqrtf(tot), 1e-12f);
  ((float4*)out)[t] = make_float4(v.x*scale, v.y*scale, v.z*scale, v.w*scale);
}

// per-row: normalize + symmetric-absmax int8 quantization.
__global__ void norm_quant_i8(const float* __restrict__ in, char* __restrict__ out,
                              float* __restrict__ srow) {
  int row = blockIdx.x;
  int t = threadIdx.x; // 0..191
  const float4* ir = (const float4*)(in + (size_t)row * DDIM);
  float4 v = ir[t];
  float ss = v.x*v.x + v.y*v.y + v.z*v.z + v.w*v.w;
  float am = fmaxf(fmaxf(fabsf(v.x), fabsf(v.y)), fmaxf(fabsf(v.z), fabsf(v.w)));
  __shared__ float sbs[3], sba[3];
  #pragma unroll
  for (int o = 32; o; o >>= 1) {
    ss += __shfl_down(ss, o);
    am = fmaxf(am, __shfl_down(am, o));
  }
  if ((t & 63) == 0) { sbs[t >> 6] = ss; sba[t >> 6] = am; }
  __syncthreads();
  float tot = sbs[0] + sbs[1] + sbs[2];
  float amx = fmaxf(fmaxf(sba[0], sba[1]), fmaxf(sba[2], 1e-30f));
  float qs = 127.0f / amx;
  int qx = (int)rintf(v.x * qs), qy = (int)rintf(v.y * qs);
  int qz = (int)rintf(v.z * qs), qw = (int)rintf(v.w * qs);
  uint packed = (uint)(qx & 0xff) | ((uint)(qy & 0xff) << 8) |
                ((uint)(qz & 0xff) << 16) | ((uint)(qw & 0xff) << 24);
  ((uint*)(out + (size_t)row * DDIM))[t] = packed;
  if (t == 0) srow[row] = amx / (127.0f * fmaxf(sqrtf(tot), 1e-12f));
}

// ---------------- RC GEMM (int8) + column max ----------------
// Block tile 256x256, grid 98x16 XCD-chunked. 256 threads, 4 waves (2Mx2N),
// wave tile 128x128 (acc 8x8 i32x4 = 256 regs; launch_bounds(256,1) gives
// the full 512-reg budget -> no spill). 12 K-tiles of 64. 3 LDS bufs x 32KB
// (A 16KB | B 16KB), quad-XOR swizzle. Body: {stage(t+2) | vmcnt(16) | bar |
// reads+64 MFMA | bar}. Arithmetic intensity 250 B-LDS/MFMA puts LDS (770cyc)
// under the MFMA floor (1312cyc/tile) — R6's 128x64 wave was LDS-BW-capped.
__global__ __launch_bounds__(256, 1)
void rc_gemm_max_kernel(const char* __restrict__ patches,
                        const char* __restrict__ concepts,
                        const float* __restrict__ sp,
                        const float* __restrict__ sc,
                        int* __restrict__ Max) {
  __shared__ __align__(16) char lds[3 * 32768];
  __shared__ float sp_lds[256];
  __shared__ float colmax[2][2][256];   // [wm][seg][col]

  const int bid0 = blockIdx.x;
  const int lin = (bid0 & 7) * 196 + (bid0 >> 3);  // bijective (1568 = 8*196)
  const int mt = lin >> 4;          // 0..97 (mt-major within XCD: B L2-hot)
  const int bn = lin & 15;
  const int tid = threadIdx.x;
  const int lane = tid & 63;
  const int wid = tid >> 6;
  const int wm = wid >> 1;   // 0..1
  const int wn = wid & 1;    // 0..1
  const int brow = mt * 256;
  const int bcol = bn * BNC;

  const char* Ab = patches  + (size_t)brow * DDIM;
  const char* Bb = concepts + (size_t)bcol * DDIM;

  sp_lds[tid] = sp[brow + tid];

  // ds_read base offsets (quad-XOR swizzle; slot invariant across frag idx)
  const int arow = wm*128 + (lane & 15);
  const int aslot = (lane >> 4) ^ (((lane & 15) >> 1) & 3);
  const int a_base = arow*64 + aslot*16;
  const int bcl = wn*128 + (lane & 15);
  const int b_base = 16384 + bcl*64 + aslot*16;
  // staging voffset; slot invariant across k2 chunks (k2*256 ≡ 0 mod 4 rows)
  const int r0 = tid >> 2;
  const int q0 = (tid & 3) ^ ((r0 >> 1) & 3);
  const int svoff = r0*DDIM + q0*16;

  i32x4 acc[8][8];
  #pragma unroll
  for (int i = 0; i < 8; ++i)
    #pragma unroll
    for (int j = 0; j < 8; ++j) { i32x4 z = {0,0,0,0}; acc[i][j] = z; }

  // stage K-tile t into buffer: A 256x64 = 16KB (4 cp/thr), B 16KB (4 cp/thr)
  auto stage = [&](int kcol, int bufi) {
    char* dst = lds + bufi * 32768;
    #pragma unroll
    for (int k2 = 0; k2 < 4; ++k2)
      async_cp16(dst + tid*16 + k2*4096, Ab + svoff + k2*(64*DDIM) + kcol);
    #pragma unroll
    for (int k2 = 0; k2 < 4; ++k2)
      async_cp16(dst + 16384 + tid*16 + k2*4096, Bb + svoff + k2*(64*DDIM) + kcol);
  };

  auto compute = [&](int bufi) {
    const char* ab = lds + bufi * 32768;
    i32x4 a[8], b[8];
    #pragma unroll
    for (int i = 0; i < 8; ++i) a[i] = *(const i32x4*)(ab + a_base + i*1024);
    #pragma unroll
    for (int j = 0; j < 8; ++j) b[j] = *(const i32x4*)(ab + b_base + j*1024);
    __builtin_amdgcn_s_setprio(1);
    #pragma unroll
    for (int i = 0; i < 8; ++i)
      #pragma unroll
      for (int j = 0; j < 8; ++j)
        acc[i][j] = __builtin_amdgcn_mfma_i32_16x16x64_i8(a[i], b[j], acc[i][j], 0, 0, 0);
    __builtin_amdgcn_s_setprio(0);
  };

  // 8 staging ops/thread/tile -> steady-state wait vmcnt(16) = 2 tiles in flight
#define BODY(T)                                                               \
  {                                                                           \
    stage(((T)+2)*64, ((T)+2)%3);                                             \
    vmwait<16>();                                                             \
    blockbar();                                                               \
    compute((T)%3);                                                           \
    blockbar();                                                               \
  }

  stage(0, 0);
  stage(64, 1);
  BODY(0) BODY(1) BODY(2) BODY(3) BODY(4)
  BODY(5) BODY(6) BODY(7) BODY(8) BODY(9)
  { vmwait<8>(); blockbar(); compute(10 % 3); blockbar(); }
  { vmwait<0>(); blockbar(); compute(11 % 3); blockbar(); }
#undef BODY

  // epilogue: dequant + segmented column max (wave's 128 rows span <= 2 images)
  float cmax[8][2];
  #pragma unroll
  for (int j = 0; j < 8; ++j) { cmax[j][0] = -3e38f; cmax[j][1] = -3e38f; }
  float scv[8];
  #pragma unroll
  for (int j = 0; j < 8; ++j) scv[j] = sc[bcol + wn*128 + j*16 + (lane & 15)];
  const int img0w = (brow + wm*128) / NPATCH;
  #pragma unroll
  for (int i = 0; i < 8; ++i) {
    #pragma unroll
    for (int e = 0; e < 4; ++e) {
      int rl = wm*128 + i*16 + (lane >> 4)*4 + e;
      float spv = sp_lds[rl];
      int seg = ((brow + rl) / NPATCH) - img0w;   // 0 or 1
      #pragma unroll
      for (int j = 0; j < 8; ++j) {
        float v = (float)acc[i][j][e] * spv * scv[j];
        cmax[j][0] = (seg == 0) ? fmaxf(cmax[j][0], v) : cmax[j][0];
        cmax[j][1] = (seg == 1) ? fmaxf(cmax[j][1], v) : cmax[j][1];
      }
    }
  }
  #pragma unroll
  for (int j = 0; j < 8; ++j) {
    #pragma unroll
    for (int s = 0; s < 2; ++s) {
      float v = cmax[j][s];
      v = fmaxf(v, __shfl_xor(v, 16));
      v = fmaxf(v, __shfl_xor(v, 32));
      cmax[j][s] = v;
    }
  }
  if (lane < 16) {
    #pragma unroll
    for (int j = 0; j < 8; ++j) {
      colmax[wm][0][wn*128 + j*16 + lane] = cmax[j][0];
      colmax[wm][1][wn*128 + j*16 + lane] = cmax[j][1];
    }
  }
  __syncthreads();
  #pragma unroll
  for (int w = 0; w < 2; ++w) {
    int col = tid;             // 0..255
    int i0 = (brow + w*128) / NPATCH;
    int i1 = (brow + w*128 + 127) / NPATCH;
    int gcol = bcol + col;
    atomicMax(&Max[(size_t)i0 * NCOLS + gcol], encf(colmax[w][0][col]));
    if (i1 != i0) atomicMax(&Max[(size_t)i1 * NCOLS + gcol], encf(colmax[w][1][col]));
  }
}

// ---------------- losses ----------------

__global__ void it_loss_kernel(const float* __restrict__ imgn, const float* __restrict__ txtn,
                               const float* __restrict__ sc, const float* __restrict__ bi,
                               float* __restrict__ acc) {
  int m = blockIdx.x;
  int c = threadIdx.x;  // 128 threads
  __shared__ __align__(16) float arow[DDIM];
  for (int k = c; k < DDIM; k += 128) arow[k] = imgn[(size_t)m * DDIM + k];
  __syncthreads();
  const float4* br = (const float4*)(txtn + (size_t)c * DDIM);
  const float4* ar = (const float4*)arow;
  float dot = 0.f;
  #pragma unroll 8
  for (int k = 0; k < DDIM/4; ++k) {
    float4 x = ar[k], y = br[k];
    dot += x.x*y.x + x.y*y.y + x.z*y.z + x.w*y.w;
  }
  float t = expf(fminf(fmaxf(sc[0], -10.f), 10.f));
  float logit = fminf(fmaxf(t*dot + bi[0], -50.f), 50.f);
  float x = (c == m) ? logit : -logit;
  float v = neg_log_sigmoid(x);
  __shared__ float sb[2];
  #pragma unroll
  for (int o = 32; o; o >>= 1) v += __shfl_down(v, o);
  if ((c & 63) == 0) sb[c >> 6] = v;
  __syncthreads();
  if (c == 0) atomicAdd(acc, sb[0] + sb[1]);
}

__global__ void rc_loss_kernel(const int* __restrict__ Max, const int* __restrict__ counts,
                               const float* __restrict__ sc, const float* __restrict__ bi,
                               float* __restrict__ acc) {
  int m = blockIdx.x;
  int v = threadIdx.x;  // 128 threads
  const int* row = Max + (size_t)m * NCOLS + (size_t)v * WCON;
  int cnt = counts[v];
  float s = 0.f;
  for (int w = 0; w < cnt; ++w) s += decf(row[w]);
  float S = s / (float)cnt;
  float t = expf(fminf(fmaxf(sc[0], -10.f), 10.f));
  float logit = fminf(fmaxf(t*S + bi[0], -50.f), 50.f);
  float x = (v == m) ? logit : -logit;
  float val = neg_log_sigmoid(x);
  __shared__ float sb[2];
  #pragma unroll
  for (int o = 32; o; o >>= 1) val += __shfl_down(val, o);
  if ((v & 63) == 0) sb[v >> 6] = val;
  __syncthreads();
  if (v == 0) atomicAdd(acc, sb[0] + sb[1]);
}

__global__ void finalize_kernel(const float* __restrict__ acc, float* __restrict__ out) {
  if (threadIdx.x == 0 && blockIdx.x == 0) {
    float it = acc[0] * (1.f / 16384.f);
    float rc = acc[1] * (1.f / 16384.f);
    out[0] = it + 0.5f * rc;
    out[1] = it;
    out[2] = rc;
  }
}

// ---------------- launch ----------------

extern "C" void kernel_launch(void* const* d_in, const int* in_sizes, int n_in,
                              void* d_out, int out_size, void* d_ws, size_t ws_size,
                              hipStream_t stream) {
  const float* image_features        = (const float*)d_in[0];
  const float* text_features         = (const float*)d_in[1];
  const float* image_token_features  = (const float*)d_in[2];
  const float* concept_text_features = (const float*)d_in[3];
  const int*   concept_counts        = (const int*)d_in[4];
  const float* logit_scale           = (const float*)d_in[5];
  const float* logit_bias            = (const float*)d_in[6];
  float* out = (float*)d_out;

  if (ws_size < WS_NEED) {
    hipMemsetAsync(d_out, 0, (size_t)out_size * sizeof(float), stream);
    return;
  }

  char* ws = (char*)d_ws;
  char*  patches_i8  = ws + PI8_OFF;
  char*  concepts_i8 = ws + CI8_OFF;
  float* sp          = (float*)(ws + SP_OFF);
  float* scq         = (float*)(ws + SC_OFF);
  float* imgn        = (float*)(ws + IMGN_OFF);
  float* txtn        = (float*)(ws + TXTN_OFF);
  int*   Maxbuf      = (int*)(ws + MAX_OFF);
  float* acc         = (float*)(ws + ACC_OFF);          // [0]=it, [1]=rc

  hipMemsetAsync(ws + ACC_OFF, 0, 256, stream);
  hipMemsetAsync(Maxbuf, 0x80, MAX_BYTES, stream);      // decodes very negative

  norm_f32_kernel<<<2*BATCH, 192, 0, stream>>>(image_features, text_features, imgn, txtn);
  norm_quant_i8<<<MTOT, 192, 0, stream>>>(image_token_features, patches_i8, sp);
  norm_quant_i8<<<NCOLS, 192, 0, stream>>>(concept_text_features, concepts_i8, scq);

  rc_gemm_max_kernel<<<NBLK, 256, 0, stream>>>(patches_i8, concepts_i8, sp, scq, Maxbuf);

  it_loss_kernel<<<BATCH, 128, 0, stream>>>(imgn, txtn, logit_scale, logit_bias, acc);
  rc_loss_kernel<<<BATCH, 128, 0, stream>>>(Maxbuf, concept_counts, logit_scale, logit_bias, acc + 1);
  finalize_kernel<<<1, 64, 0, stream>>>(acc, out);
}

// Round 11
// 162.987 us; speedup vs baseline: 2.2236x; 1.1361x over previous
//
#include <hip/hip_runtime.h>
#include <hip/hip_bf16.h>
#include <cstdint>

using i32x4 = __attribute__((ext_vector_type(4))) int;

// Problem dims
#define BATCH   128
#define NPATCH  196
#define MTOT    25088   // 128*196 = 112*224 exactly
#define MTM     224     // rows per M-tile
#define MT      112     // M-tiles
#define DDIM    768
#define WCON    32
#define NCOLS   4096    // BATCH*WCON
#define BNC     128     // cols per block
#define NBN     32      // NCOLS/BNC
#define NT      12      // K-tiles of 64
#define NBLK    3584    // MT*NBN = 7 * 512 exactly (zero launch-round tail)
#define BUFS    22528   // A 14336 + B 8192
#define ABYTES  14336   // 224*64
#define NCHA    896     // A 16B-chunks per tile

// ws layout (bytes), each 256-aligned
#define PI8_OFF   0ull
#define PI8_BYTES ((size_t)MTOT*DDIM)
#define CI8_OFF   (PI8_OFF + PI8_BYTES)
#define CI8_BYTES (4096ull*DDIM)
#define SP_OFF    (CI8_OFF + CI8_BYTES)
#define SP_BYTES  ((size_t)MTOT*4)
#define SC_OFF    (SP_OFF + SP_BYTES)
#define SC_BYTES  (4096ull*4)
#define IMGN_OFF  (SC_OFF + SC_BYTES)
#define F_BYTES   (128ull*768*4)
#define TXTN_OFF  (IMGN_OFF + F_BYTES)
#define MAX_OFF   (TXTN_OFF + F_BYTES)
#define MAX_BYTES (128ull*4096*4)
#define ACC_OFF   (MAX_OFF + MAX_BYTES)
#define WS_NEED   (ACC_OFF + 256ull)

__device__ __forceinline__ void async_cp16(void* lds_p, const void* g) {
  __builtin_amdgcn_global_load_lds(
      (const __attribute__((address_space(1))) unsigned int*)g,
      (__attribute__((address_space(3))) unsigned int*)lds_p, 16, 0, 0);
}

__device__ __forceinline__ float neg_log_sigmoid(float x) {
  return (x > 0.f) ? log1pf(expf(-x)) : (log1pf(expf(x)) - x);
}

// monotone float<->int encoding for atomicMax on floats (no NaNs here)
__device__ __forceinline__ int encf(float f) {
  int i = __float_as_int(f);
  return i >= 0 ? i : (i ^ 0x7FFFFFFF);
}
__device__ __forceinline__ float decf(int e) {
  return __int_as_float(e >= 0 ? e : (e ^ 0x7FFFFFFF));
}

template<int VM>
__device__ __forceinline__ void vmwait() {
  asm volatile("s_waitcnt vmcnt(%0)" :: "n"(VM) : "memory");
}
__device__ __forceinline__ void blockbar() {
  asm volatile("" ::: "memory");
  __builtin_amdgcn_s_barrier();
  asm volatile("" ::: "memory");
}

// ---------------- normalization kernels ----------------

// rows 0..127: image_features -> imgn ; rows 128..255: text_features -> txtn
__global__ void norm_f32_kernel(const float* __restrict__ ina, const float* __restrict__ inb,
                                float* __restrict__ outa, float* __restrict__ outb) {
  int row = blockIdx.x;
  int t = threadIdx.x; // 0..191
  const float* in = (row < BATCH) ? ina + (size_t)row * DDIM : inb + (size_t)(row - BATCH) * DDIM;
  float* out = (row < BATCH) ? outa + (size_t)row * DDIM : outb + (size_t)(row - BATCH) * DDIM;
  float4 v = ((const float4*)in)[t];
  float ss = v.x*v.x + v.y*v.y + v.z*v.z + v.w*v.w;
  __shared__ float sb[3];
  #pragma unroll
  for (int o = 32; o; o >>= 1) ss += __shfl_down(ss, o);
  if ((t & 63) == 0) sb[t >> 6] = ss;
  __syncthreads();
  float tot = sb[0] + sb[1] + sb[2];
  float scale = 1.0f / fmaxf(sqrtf(tot), 1e-12f);
  ((float4*)out)[t] = make_float4(v.x*scale, v.y*scale, v.z*scale, v.w*scale);
}

// per-row: normalize + symmetric-absmax int8 quantization.
// blocks 0..MTOT-1: patches; blocks MTOT..MTOT+NCOLS-1: concepts.
__global__ void norm_quant_i8(const float* __restrict__ inp, char* __restrict__ outp,
                              float* __restrict__ srowp,
                              const float* __restrict__ inc, char* __restrict__ outc,
                              float* __restrict__ srowc) {
  int bid = blockIdx.x;
  bool isP = bid < MTOT;
  int row = isP ? bid : bid - MTOT;
  const float* in = (isP ? inp : inc) + (size_t)row * DDIM;
  char* out = (isP ? outp : outc) + (size_t)row * DDIM;
  float* srow = (isP ? srowp : srowc) + row;
  int t = threadIdx.x; // 0..191
  float4 v = ((const float4*)in)[t];
  float ss = v.x*v.x + v.y*v.y + v.z*v.z + v.w*v.w;
  float am = fmaxf(fmaxf(fabsf(v.x), fabsf(v.y)), fmaxf(fabsf(v.z), fabsf(v.w)));
  __shared__ float sbs[3], sba[3];
  #pragma unroll
  for (int o = 32; o; o >>= 1) {
    ss += __shfl_down(ss, o);
    am = fmaxf(am, __shfl_down(am, o));
  }
  if ((t & 63) == 0) { sbs[t >> 6] = ss; sba[t >> 6] = am; }
  __syncthreads();
  float tot = sbs[0] + sbs[1] + sbs[2];
  float amx = fmaxf(fmaxf(sba[0], sba[1]), fmaxf(sba[2], 1e-30f));
  float qs = 127.0f / amx;
  int qx = (int)rintf(v.x * qs), qy = (int)rintf(v.y * qs);
  int qz = (int)rintf(v.z * qs), qw = (int)rintf(v.w * qs);
  uint packed = (uint)(qx & 0xff) | ((uint)(qy & 0xff) << 8) |
                ((uint)(qz & 0xff) << 16) | ((uint)(qw & 0xff) << 24);
  ((uint*)out)[t] = packed;
  if (t == 0) srow[0] = amx / (127.0f * fmaxf(sqrtf(tot), 1e-12f));
}

// ---------------- RC GEMM (int8) + column max ----------------
// M-tile 224 x col-chunk 128; grid 112x32 = 3584 = 7*512 (zero round tail
// at 2 blocks/CU). 256 threads, 4 waves (2Mx2N), wave tile 112x64 (M_rep 7).
// 12 K-tiles of 64. 3 LDS bufs x 22528B (A 14336 | B 8192), quad-XOR swizzle.
// R6 body: {stage(t+2) | counted vmwait | bar | reads+28 MFMA | bar}.
// Staging: waves 0,1 = 6 cp/tile (4A+2B), waves 2,3 = 5 (3A+2B) -> per-wave
// counted vmwait (12/10 steady; 6/5, 0 tail).
__global__ __launch_bounds__(256, 2)
void rc_gemm_max_kernel(const char* __restrict__ patches,
                        const char* __restrict__ concepts,
                        const float* __restrict__ sp,
                        const float* __restrict__ sc,
                        int* __restrict__ Max) {
  __shared__ __align__(16) char lds[3 * BUFS];
  __shared__ float sp_lds[MTM];
  __shared__ float colmax[2][2][128];   // [wm][seg][col]

  const int bid0 = blockIdx.x;
  const int lin = (bid0 & 7) * 448 + (bid0 >> 3);  // bijective (3584 = 8*448)
  const int mt = lin >> 5;          // 0..111 (mt-major within XCD: B L2-hot)
  const int bn = lin & 31;
  const int tid = threadIdx.x;
  const int lane = tid & 63;
  const int wid = tid >> 6;
  const int wm = wid >> 1;   // 0..1
  const int wn = wid & 1;    // 0..1
  const bool loww = (wid < 2);     // waves 0,1 issue 6 staging ops/tile
  const int brow = mt * MTM;
  const int bcol = bn * BNC;

  const char* Ab = patches  + (size_t)brow * DDIM;
  const char* Bb = concepts + (size_t)bcol * DDIM;

  if (tid < MTM) sp_lds[tid] = sp[brow + tid];

  // ds_read base offsets (quad-XOR swizzle; slot invariant across frag idx)
  const int arow = wm*112 + (lane & 15);
  const int aslot = (lane >> 4) ^ (((lane & 15) >> 1) & 3);
  const int a_base = arow*64 + aslot*16;
  const int bcl = wn*64 + (lane & 15);
  const int b_base = ABYTES + bcl*64 + aslot*16;
  // staging voffset; slot invariant across k2 row-groups (multiples of 4 rows)
  const int r0 = tid >> 2;
  const int q0 = (tid & 3) ^ ((r0 >> 1) & 3);
  const int svoff = r0*DDIM + q0*16;

  i32x4 acc[7][4];
  #pragma unroll
  for (int i = 0; i < 7; ++i)
    #pragma unroll
    for (int j = 0; j < 4; ++j) { i32x4 z = {0,0,0,0}; acc[i][j] = z; }

  // stage K-tile: A 896 chunks (3/thr + 1 extra for tid<128), B 512 (2/thr)
  auto stage = [&](int kcol, int bufi) {
    char* dst = lds + bufi * BUFS;
    #pragma unroll
    for (int k2 = 0; k2 < 3; ++k2)
      async_cp16(dst + tid*16 + k2*4096, Ab + svoff + k2*(64*DDIM) + kcol);
    if (tid < 128)   // chunk 768+tid -> row 192+(tid>>2); q pattern == q0
      async_cp16(dst + 12288 + tid*16, Ab + svoff + 192*DDIM + kcol);
    #pragma unroll
    for (int k2 = 0; k2 < 2; ++k2)
      async_cp16(dst + ABYTES + tid*16 + k2*4096, Bb + svoff + k2*(64*DDIM) + kcol);
  };

  auto compute = [&](int bufi) {
    const char* ab = lds + bufi * BUFS;
    i32x4 a[7], b[4];
    #pragma unroll
    for (int i = 0; i < 7; ++i) a[i] = *(const i32x4*)(ab + a_base + i*1024);
    #pragma unroll
    for (int j = 0; j < 4; ++j) b[j] = *(const i32x4*)(ab + b_base + j*1024);
    __builtin_amdgcn_s_setprio(1);
    #pragma unroll
    for (int i = 0; i < 7; ++i)
      #pragma unroll
      for (int j = 0; j < 4; ++j)
        acc[i][j] = __builtin_amdgcn_mfma_i32_16x16x64_i8(a[i], b[j], acc[i][j], 0, 0, 0);
    __builtin_amdgcn_s_setprio(0);
  };

#define BODY(T)                                                               \
  {                                                                           \
    stage(((T)+2)*64, ((T)+2)%3);                                             \
    if (loww) vmwait<12>(); else vmwait<10>();                                \
    blockbar();                                                               \
    compute((T)%3);                                                           \
    blockbar();                                                               \
  }

  stage(0, 0);
  stage(64, 1);
  BODY(0) BODY(1) BODY(2) BODY(3) BODY(4)
  BODY(5) BODY(6) BODY(7) BODY(8) BODY(9)
  { if (loww) vmwait<6>(); else vmwait<5>();
    blockbar(); compute(10 % 3); blockbar(); }
  { vmwait<0>(); blockbar(); compute(11 % 3); blockbar(); }
#undef BODY

  // epilogue: dequant + segmented column max (112-row wave spans <= 2 images)
  float cmax[4][2];
  #pragma unroll
  for (int j = 0; j < 4; ++j) { cmax[j][0] = -3e38f; cmax[j][1] = -3e38f; }
  float scv[4];
  #pragma unroll
  for (int j = 0; j < 4; ++j) scv[j] = sc[bcol + wn*64 + j*16 + (lane & 15)];
  const int img0w = (brow + wm*112) / NPATCH;
  #pragma unroll
  for (int i = 0; i < 7; ++i) {
    #pragma unroll
    for (int e = 0; e < 4; ++e) {
      int rl = wm*112 + i*16 + (lane >> 4)*4 + e;
      float spv = sp_lds[rl];
      int seg = ((brow + rl) / NPATCH) - img0w;   // 0 or 1
      #pragma unroll
      for (int j = 0; j < 4; ++j) {
        float v = (float)acc[i][j][e] * spv * scv[j];
        cmax[j][0] = (seg == 0) ? fmaxf(cmax[j][0], v) : cmax[j][0];
        cmax[j][1] = (seg == 1) ? fmaxf(cmax[j][1], v) : cmax[j][1];
      }
    }
  }
  #pragma unroll
  for (int j = 0; j < 4; ++j) {
    #pragma unroll
    for (int s = 0; s < 2; ++s) {
      float v = cmax[j][s];
      v = fmaxf(v, __shfl_xor(v, 16));
      v = fmaxf(v, __shfl_xor(v, 32));
      cmax[j][s] = v;
    }
  }
  if (lane < 16) {
    #pragma unroll
    for (int j = 0; j < 4; ++j) {
      colmax[wm][0][wn*64 + j*16 + lane] = cmax[j][0];
      colmax[wm][1][wn*64 + j*16 + lane] = cmax[j][1];
    }
  }
  __syncthreads();
  {
    int w = tid >> 7;          // 0..1 (wm)
    int col = tid & 127;
    int i0 = (brow + w*112) / NPATCH;
    int i1 = (brow + w*112 + 111) / NPATCH;
    int gcol = bcol + col;
    atomicMax(&Max[(size_t)i0 * NCOLS + gcol], encf(colmax[w][0][col]));
    if (i1 != i0) atomicMax(&Max[(size_t)i1 * NCOLS + gcol], encf(colmax[w][1][col]));
  }
}

// ---------------- losses ----------------

__global__ void it_loss_kernel(const float* __restrict__ imgn, const float* __restrict__ txtn,
                               const float* __restrict__ sc, const float* __restrict__ bi,
                               float* __restrict__ acc) {
  int m = blockIdx.x;
  int c = threadIdx.x;  // 128 threads
  __shared__ __align__(16) float arow[DDIM];
  for (int k = c; k < DDIM; k += 128) arow[k] = imgn[(size_t)m * DDIM + k];
  __syncthreads();
  const float4* br = (const float4*)(txtn + (size_t)c * DDIM);
  const float4* ar = (const float4*)arow;
  float dot = 0.f;
  #pragma unroll 8
  for (int k = 0; k < DDIM/4; ++k) {
    float4 x = ar[k], y = br[k];
    dot += x.x*y.x + x.y*y.y + x.z*y.z + x.w*y.w;
  }
  float t = expf(fminf(fmaxf(sc[0], -10.f), 10.f));
  float logit = fminf(fmaxf(t*dot + bi[0], -50.f), 50.f);
  float x = (c == m) ? logit : -logit;
  float v = neg_log_sigmoid(x);
  __shared__ float sb[2];
  #pragma unroll
  for (int o = 32; o; o >>= 1) v += __shfl_down(v, o);
  if ((c & 63) == 0) sb[c >> 6] = v;
  __syncthreads();
  if (c == 0) atomicAdd(acc, sb[0] + sb[1]);
}

__global__ void rc_loss_kernel(const int* __restrict__ Max, const int* __restrict__ counts,
                               const float* __restrict__ sc, const float* __restrict__ bi,
                               float* __restrict__ acc) {
  int m = blockIdx.x;
  int v = threadIdx.x;  // 128 threads
  const int* row = Max + (size_t)m * NCOLS + (size_t)v * WCON;
  int cnt = counts[v];
  float s = 0.f;
  for (int w = 0; w < cnt; ++w) s += decf(row[w]);
  float S = s / (float)cnt;
  float t = expf(fminf(fmaxf(sc[0], -10.f), 10.f));
  float logit = fminf(fmaxf(t*S + bi[0], -50.f), 50.f);
  float x = (v == m) ? logit : -logit;
  float val = neg_log_sigmoid(x);
  __shared__ float sb[2];
  #pragma unroll
  for (int o = 32; o; o >>= 1) val += __shfl_down(val, o);
  if ((v & 63) == 0) sb[v >> 6] = val;
  __syncthreads();
  if (v == 0) atomicAdd(acc, sb[0] + sb[1]);
}

__global__ void finalize_kernel(const float* __restrict__ acc, float* __restrict__ out) {
  if (threadIdx.x == 0 && blockIdx.x == 0) {
    float it = acc[0] * (1.f / 16384.f);
    float rc = acc[1] * (1.f / 16384.f);
    out[0] = it + 0.5f * rc;
    out[1] = it;
    out[2] = rc;
  }
}

// ---------------- launch ----------------

extern "C" void kernel_launch(void* const* d_in, const int* in_sizes, int n_in,
                              void* d_out, int out_size, void* d_ws, size_t ws_size,
                              hipStream_t stream) {
  const float* image_features        = (const float*)d_in[0];
  const float* text_features         = (const float*)d_in[1];
  const float* image_token_features  = (const float*)d_in[2];
  const float* concept_text_features = (const float*)d_in[3];
  const int*   concept_counts        = (const int*)d_in[4];
  const float* logit_scale           = (const float*)d_in[5];
  const float* logit_bias            = (const float*)d_in[6];
  float* out = (float*)d_out;

  if (ws_size < WS_NEED) {
    hipMemsetAsync(d_out, 0, (size_t)out_size * sizeof(float), stream);
    return;
  }

  char* ws = (char*)d_ws;
  char*  patches_i8  = ws + PI8_OFF;
  char*  concepts_i8 = ws + CI8_OFF;
  float* sp          = (float*)(ws + SP_OFF);
  float* scq         = (float*)(ws + SC_OFF);
  float* imgn        = (float*)(ws + IMGN_OFF);
  float* txtn        = (float*)(ws + TXTN_OFF);
  int*   Maxbuf      = (int*)(ws + MAX_OFF);
  float* acc         = (float*)(ws + ACC_OFF);          // [0]=it, [1]=rc

  hipMemsetAsync(ws + ACC_OFF, 0, 256, stream);
  hipMemsetAsync(Maxbuf, 0x80, MAX_BYTES, stream);      // decodes very negative

  norm_f32_kernel<<<2*BATCH, 192, 0, stream>>>(image_features, text_features, imgn, txtn);
  norm_quant_i8<<<MTOT + NCOLS, 192, 0, stream>>>(image_token_features, patches_i8, sp,
                                                  concept_text_features, concepts_i8, scq);

  rc_gemm_max_kernel<<<NBLK, 256, 0, stream>>>(patches_i8, concepts_i8, sp, scq, Maxbuf);

  it_loss_kernel<<<BATCH, 128, 0, stream>>>(imgn, txtn, logit_scale, logit_bias, acc);
  rc_loss_kernel<<<BATCH, 128, 0, stream>>>(Maxbuf, concept_counts, logit_scale, logit_bias, acc + 1);
  finalize_kernel<<<1, 64, 0, stream>>>(acc, out);
}

// Round 12
// 149.548 us; speedup vs baseline: 2.4234x; 1.0899x over previous
//
#include <hip/hip_runtime.h>
#include <hip/hip_bf16.h>
#include <cstdint>

using i32x4 = __attribute__((ext_vector_type(4))) int;

// Problem dims
#define BATCH   128
#define NPATCH  196
#define MTOT    25088   // 128*196, = 98*256 exactly
#define MT      98      // M-tiles of 256
#define DDIM    768
#define WCON    32
#define NCOLS   4096    // BATCH*WCON
#define BNC     128     // cols per block
#define NBN     32      // NCOLS/BNC
#define NT      12      // K-tiles of 64
#define NBLK    3136    // MT*NBN

// ws layout (bytes), each 256-aligned
#define PI8_OFF   0ull
#define PI8_BYTES ((size_t)MTOT*DDIM)
#define CI8_OFF   (PI8_OFF + PI8_BYTES)
#define CI8_BYTES (4096ull*DDIM)
#define SP_OFF    (CI8_OFF + CI8_BYTES)
#define SP_BYTES  ((size_t)MTOT*4)
#define SC_OFF    (SP_OFF + SP_BYTES)
#define SC_BYTES  (4096ull*4)
#define IMGN_OFF  (SC_OFF + SC_BYTES)
#define F_BYTES   (128ull*768*4)
#define TXTN_OFF  (IMGN_OFF + F_BYTES)
#define MAX_OFF   (TXTN_OFF + F_BYTES)
#define MAX_BYTES (128ull*4096*4)
#define ACC_OFF   (MAX_OFF + MAX_BYTES)
#define WS_NEED   (ACC_OFF + 256ull)

__device__ __forceinline__ void async_cp16(void* lds_p, const void* g) {
  __builtin_amdgcn_global_load_lds(
      (const __attribute__((address_space(1))) unsigned int*)g,
      (__attribute__((address_space(3))) unsigned int*)lds_p, 16, 0, 0);
}

__device__ __forceinline__ float neg_log_sigmoid(float x) {
  return (x > 0.f) ? log1pf(expf(-x)) : (log1pf(expf(x)) - x);
}

// monotone float<->int encoding for atomicMax on floats (no NaNs here)
__device__ __forceinline__ int encf(float f) {
  int i = __float_as_int(f);
  return i >= 0 ? i : (i ^ 0x7FFFFFFF);
}
__device__ __forceinline__ float decf(int e) {
  return __int_as_float(e >= 0 ? e : (e ^ 0x7FFFFFFF));
}

template<int VM>
__device__ __forceinline__ void vmwait() {
  asm volatile("s_waitcnt vmcnt(%0)" :: "n"(VM) : "memory");
}
__device__ __forceinline__ void blockbar() {
  asm volatile("" ::: "memory");
  __builtin_amdgcn_s_barrier();
  asm volatile("" ::: "memory");
}

// ---------------- unified preprocessing kernel ----------------
// blocks [0, MTOT)                : patch rows -> i8 quant + scale
// blocks [MTOT, MTOT+NCOLS)       : concept rows -> i8 quant + scale
// blocks [MTOT+NCOLS, +BATCH)     : image cls -> f32 normalize
// blocks [MTOT+NCOLS+BATCH, +BATCH): text cls -> f32 normalize
__global__ void preproc_kernel(const float* __restrict__ tokp, char* __restrict__ outp,
                               float* __restrict__ srowp,
                               const float* __restrict__ tokc, char* __restrict__ outc,
                               float* __restrict__ srowc,
                               const float* __restrict__ imgf, float* __restrict__ imgn,
                               const float* __restrict__ txtf, float* __restrict__ txtn) {
  int bid = blockIdx.x;
  int t = threadIdx.x; // 0..191
  __shared__ float sbs[3], sba[3];

  const float* in;
  char* qout = nullptr;
  float* srow = nullptr;
  float* fout = nullptr;
  if (bid < MTOT) {
    in = tokp + (size_t)bid * DDIM; qout = outp; srow = srowp + bid;
    qout += (size_t)bid * DDIM;
  } else if (bid < MTOT + NCOLS) {
    int r = bid - MTOT;
    in = tokc + (size_t)r * DDIM; qout = outc + (size_t)r * DDIM; srow = srowc + r;
  } else if (bid < MTOT + NCOLS + BATCH) {
    int r = bid - MTOT - NCOLS;
    in = imgf + (size_t)r * DDIM; fout = imgn + (size_t)r * DDIM;
  } else {
    int r = bid - MTOT - NCOLS - BATCH;
    in = txtf + (size_t)r * DDIM; fout = txtn + (size_t)r * DDIM;
  }

  float4 v = ((const float4*)in)[t];
  float ss = v.x*v.x + v.y*v.y + v.z*v.z + v.w*v.w;
  float am = fmaxf(fmaxf(fabsf(v.x), fabsf(v.y)), fmaxf(fabsf(v.z), fabsf(v.w)));
  #pragma unroll
  for (int o = 32; o; o >>= 1) {
    ss += __shfl_down(ss, o);
    am = fmaxf(am, __shfl_down(am, o));
  }
  if ((t & 63) == 0) { sbs[t >> 6] = ss; sba[t >> 6] = am; }
  __syncthreads();
  float tot = sbs[0] + sbs[1] + sbs[2];
  float amx = fmaxf(fmaxf(sba[0], sba[1]), fmaxf(sba[2], 1e-30f));

  if (qout) {
    float qs = 127.0f / amx;
    int qx = (int)rintf(v.x * qs), qy = (int)rintf(v.y * qs);
    int qz = (int)rintf(v.z * qs), qw = (int)rintf(v.w * qs);
    uint packed = (uint)(qx & 0xff) | ((uint)(qy & 0xff) << 8) |
                  ((uint)(qz & 0xff) << 16) | ((uint)(qw & 0xff) << 24);
    ((uint*)qout)[t] = packed;
    if (t == 0) srow[0] = amx / (127.0f * fmaxf(sqrtf(tot), 1e-12f));
  } else {
    float scale = 1.0f / fmaxf(sqrtf(tot), 1e-12f);
    ((float4*)fout)[t] = make_float4(v.x*scale, v.y*scale, v.z*scale, v.w*scale);
  }
}

// ---------------- RC GEMM (int8) + column max (R6 verbatim, 111.4 us) ------
// Packed A: 25088x768 i8. Grid 98 M-tiles x 32 N-tiles. 256 threads, 4 waves
// (2Mx2N), wave tile 128x64. BK=64, 12 K-tiles. 3 LDS bufs x 24KB, quad-XOR
// swizzle. Body: {stage(t+2) | vmcnt(12) | bar | reads+32 MFMA | bar}.
__global__ __launch_bounds__(256, 2)
void rc_gemm_max_kernel(const char* __restrict__ patches,
                        const char* __restrict__ concepts,
                        const float* __restrict__ sp,
                        const float* __restrict__ sc,
                        int* __restrict__ Max) {
  __shared__ __align__(16) char lds[3 * 24576];
  __shared__ float sp_lds[256];
  __shared__ float colmax[2][2][128];   // [wm][seg][col]

  const int bid0 = blockIdx.x;
  const int lin = (bid0 & 7) * 392 + (bid0 >> 3);  // bijective (3136 = 8*392)
  const int mt = lin >> 5;          // mt-major within XCD: B stays L2-hot
  const int bn = lin & 31;
  const int tid = threadIdx.x;
  const int lane = tid & 63;
  const int wid = tid >> 6;
  const int wm = wid >> 1;   // 0..1
  const int wn = wid & 1;    // 0..1
  const int brow = mt * 256;
  const int bcol = bn * BNC;

  const char* Ab = patches  + (size_t)brow * DDIM;
  const char* Bb = concepts + (size_t)bcol * DDIM;

  sp_lds[tid] = sp[brow + tid];

  // ds_read base offsets (quad-XOR swizzle; slot invariant across frag idx)
  const int arow = wm*128 + (lane & 15);
  const int aslot = (lane >> 4) ^ (((lane & 15) >> 1) & 3);
  const int a_base = arow*64 + aslot*16;
  const int bcl = wn*64 + (lane & 15);
  const int b_base = 16384 + bcl*64 + aslot*16;
  // staging voffset (element==byte for i8); slot invariant across k2 chunks
  const int r0 = tid >> 2;
  const int q0 = (tid & 3) ^ ((r0 >> 1) & 3);
  const int svoff = r0*DDIM + q0*16;

  i32x4 acc[8][4];
  #pragma unroll
  for (int i = 0; i < 8; ++i)
    #pragma unroll
    for (int j = 0; j < 4; ++j) { i32x4 z = {0,0,0,0}; acc[i][j] = z; }

  // stage K-tile t into explicit buffer: A 16KB (4 cp/thr), B 8KB (2 cp/thr)
  auto stage = [&](int t, int bufi) {
    char* dst = lds + bufi * 24576;
    const int kcol = t * 64;
    #pragma unroll
    for (int k2 = 0; k2 < 4; ++k2)
      async_cp16(dst + tid*16 + k2*4096, Ab + svoff + k2*(64*DDIM) + kcol);
    #pragma unroll
    for (int k2 = 0; k2 < 2; ++k2)
      async_cp16(dst + 16384 + tid*16 + k2*4096, Bb + svoff + k2*(64*DDIM) + kcol);
  };

  auto compute = [&](int bufi) {
    const char* ab = lds + bufi * 24576;
    i32x4 a[8], b[4];
    #pragma unroll
    for (int i = 0; i < 8; ++i) a[i] = *(const i32x4*)(ab + a_base + i*1024);
    #pragma unroll
    for (int j = 0; j < 4; ++j) b[j] = *(const i32x4*)(ab + b_base + j*1024);
    __builtin_amdgcn_s_setprio(1);
    #pragma unroll
    for (int i = 0; i < 8; ++i)
      #pragma unroll
      for (int j = 0; j < 4; ++j)
        acc[i][j] = __builtin_amdgcn_mfma_i32_16x16x64_i8(a[i], b[j], acc[i][j], 0, 0, 0);
    __builtin_amdgcn_s_setprio(0);
  };

#define TILE(T, VMN, DOSTAGE)                                                 \
  {                                                                           \
    if (DOSTAGE) stage((T) + 2, ((T) + 2) % 3);                               \
    vmwait<VMN>();                                                            \
    blockbar();                                                               \
    compute((T) % 3);                                                         \
    blockbar();                                                               \
  }

  stage(0, 0);
  stage(1, 1);
  TILE(0, 12, 1)  TILE(1, 12, 1)  TILE(2, 12, 1)  TILE(3, 12, 1)
  TILE(4, 12, 1)  TILE(5, 12, 1)  TILE(6, 12, 1)  TILE(7, 12, 1)
  TILE(8, 12, 1)  TILE(9, 12, 1)  TILE(10, 6, 0)  TILE(11, 0, 0)
#undef TILE

  // epilogue: dequant + segmented column max (wave's 128 rows span <= 2 images)
  float cmax[4][2];
  #pragma unroll
  for (int j = 0; j < 4; ++j) { cmax[j][0] = -3e38f; cmax[j][1] = -3e38f; }
  float scv[4];
  #pragma unroll
  for (int j = 0; j < 4; ++j) scv[j] = sc[bcol + wn*64 + j*16 + (lane & 15)];
  const int img0w = (brow + wm*128) / NPATCH;
  #pragma unroll
  for (int i = 0; i < 8; ++i) {
    #pragma unroll
    for (int e = 0; e < 4; ++e) {
      int rl = wm*128 + i*16 + (lane >> 4)*4 + e;
      float spv = sp_lds[rl];
      int seg = ((brow + rl) / NPATCH) - img0w;   // 0 or 1
      #pragma unroll
      for (int j = 0; j < 4; ++j) {
        float v = (float)acc[i][j][e] * spv * scv[j];
        cmax[j][0] = (seg == 0) ? fmaxf(cmax[j][0], v) : cmax[j][0];
        cmax[j][1] = (seg == 1) ? fmaxf(cmax[j][1], v) : cmax[j][1];
      }
    }
  }
  #pragma unroll
  for (int j = 0; j < 4; ++j) {
    #pragma unroll
    for (int s = 0; s < 2; ++s) {
      float v = cmax[j][s];
      v = fmaxf(v, __shfl_xor(v, 16));
      v = fmaxf(v, __shfl_xor(v, 32));
      cmax[j][s] = v;
    }
  }
  if (lane < 16) {
    #pragma unroll
    for (int j = 0; j < 4; ++j) {
      colmax[wm][0][wn*64 + j*16 + lane] = cmax[j][0];
      colmax[wm][1][wn*64 + j*16 + lane] = cmax[j][1];
    }
  }
  __syncthreads();
  {
    int w = tid >> 7;          // 0..1 (wm)
    int col = tid & 127;
    int i0 = (brow + w*128) / NPATCH;
    int i1 = (brow + w*128 + 127) / NPATCH;
    int gcol = bcol + col;
    atomicMax(&Max[(size_t)i0 * NCOLS + gcol], encf(colmax[w][0][col]));
    if (i1 != i0) atomicMax(&Max[(size_t)i1 * NCOLS + gcol], encf(colmax[w][1][col]));
  }
}

// ---------------- fused losses ----------------
// blocks 0..127: IT loss row m; blocks 128..255: RC loss row m-128.
__global__ void loss_kernel(const float* __restrict__ imgn, const float* __restrict__ txtn,
                            const int* __restrict__ Max, const int* __restrict__ counts,
                            const float* __restrict__ sc, const float* __restrict__ bi,
                            float* __restrict__ acc) {
  int bid = blockIdx.x;
  int c = threadIdx.x;  // 128 threads
  float t = expf(fminf(fmaxf(sc[0], -10.f), 10.f));
  float val;
  int m;
  if (bid < BATCH) {
    m = bid;
    __shared__ __align__(16) float arow[DDIM];
    for (int k = c; k < DDIM; k += 128) arow[k] = imgn[(size_t)m * DDIM + k];
    __syncthreads();
    const float4* br = (const float4*)(txtn + (size_t)c * DDIM);
    const float4* ar = (const float4*)arow;
    float dot = 0.f;
    #pragma unroll 8
    for (int k = 0; k < DDIM/4; ++k) {
      float4 x = ar[k], y = br[k];
      dot += x.x*y.x + x.y*y.y + x.z*y.z + x.w*y.w;
    }
    float logit = fminf(fmaxf(t*dot + bi[0], -50.f), 50.f);
    val = neg_log_sigmoid((c == m) ? logit : -logit);
  } else {
    m = bid - BATCH;
    const int* row = Max + (size_t)m * NCOLS + (size_t)c * WCON;
    int cnt = counts[c];
    float s = 0.f;
    for (int w = 0; w < cnt; ++w) s += decf(row[w]);
    float S = s / (float)cnt;
    float logit = fminf(fmaxf(t*S + bi[0], -50.f), 50.f);
    val = neg_log_sigmoid((c == m) ? logit : -logit);
  }
  __shared__ float sb[2];
  #pragma unroll
  for (int o = 32; o; o >>= 1) val += __shfl_down(val, o);
  if ((c & 63) == 0) sb[c >> 6] = val;
  __syncthreads();
  if (c == 0) atomicAdd(acc + (bid < BATCH ? 0 : 1), sb[0] + sb[1]);
}

__global__ void finalize_kernel(const float* __restrict__ acc, float* __restrict__ out) {
  if (threadIdx.x == 0 && blockIdx.x == 0) {
    float it = acc[0] * (1.f / 16384.f);
    float rc = acc[1] * (1.f / 16384.f);
    out[0] = it + 0.5f * rc;
    out[1] = it;
    out[2] = rc;
  }
}

// ---------------- launch ----------------

extern "C" void kernel_launch(void* const* d_in, const int* in_sizes, int n_in,
                              void* d_out, int out_size, void* d_ws, size_t ws_size,
                              hipStream_t stream) {
  const float* image_features        = (const float*)d_in[0];
  const float* text_features         = (const float*)d_in[1];
  const float* image_token_features  = (const float*)d_in[2];
  const float* concept_text_features = (const float*)d_in[3];
  const int*   concept_counts        = (const int*)d_in[4];
  const float* logit_scale           = (const float*)d_in[5];
  const float* logit_bias            = (const float*)d_in[6];
  float* out = (float*)d_out;

  if (ws_size < WS_NEED) {
    hipMemsetAsync(d_out, 0, (size_t)out_size * sizeof(float), stream);
    return;
  }

  char* ws = (char*)d_ws;
  char*  patches_i8  = ws + PI8_OFF;
  char*  concepts_i8 = ws + CI8_OFF;
  float* sp          = (float*)(ws + SP_OFF);
  float* scq         = (float*)(ws + SC_OFF);
  float* imgn        = (float*)(ws + IMGN_OFF);
  float* txtn        = (float*)(ws + TXTN_OFF);
  int*   Maxbuf      = (int*)(ws + MAX_OFF);
  float* acc         = (float*)(ws + ACC_OFF);          // [0]=it, [1]=rc

  hipMemsetAsync(ws + ACC_OFF, 0, 256, stream);
  hipMemsetAsync(Maxbuf, 0x80, MAX_BYTES, stream);      // decodes very negative

  preproc_kernel<<<MTOT + NCOLS + 2*BATCH, 192, 0, stream>>>(
      image_token_features, patches_i8, sp,
      concept_text_features, concepts_i8, scq,
      image_features, imgn, text_features, txtn);

  rc_gemm_max_kernel<<<NBLK, 256, 0, stream>>>(patches_i8, concepts_i8, sp, scq, Maxbuf);

  loss_kernel<<<2*BATCH, 128, 0, stream>>>(imgn, txtn, Maxbuf, concept_counts,
                                           logit_scale, logit_bias, acc);
  finalize_kernel<<<1, 64, 0, stream>>>(acc, out);
}

// Round 13
// 117.466 us; speedup vs baseline: 3.0853x; 1.2731x over previous
//
#include <hip/hip_runtime.h>
#include <hip/hip_bf16.h>
#include <cstdint>

using i32x4 = __attribute__((ext_vector_type(4))) int;

// Problem dims
#define BATCH   128
#define NPATCH  196
#define MTOT    25088   // 128*196, = 98*256 exactly
#define MT      98      // M-tiles of 256
#define DDIM    768
#define WCON    32
#define NCOLS   4096    // BATCH*WCON
#define BNC     128     // cols per block
#define NBN     32      // NCOLS/BNC
#define NT      12      // K-tiles of 64
#define NBLK    3136    // MT*NBN (fixed grid; excess blocks early-exit)

// ws layout (bytes), each 256-aligned
#define PI8_OFF   0ull
#define PI8_BYTES ((size_t)MTOT*DDIM)
#define CI8_OFF   (PI8_OFF + PI8_BYTES)
#define CI8_BYTES (4096ull*DDIM)
#define SP_OFF    (CI8_OFF + CI8_BYTES)
#define SP_BYTES  ((size_t)MTOT*4)
#define SC_OFF    (SP_OFF + SP_BYTES)
#define SC_BYTES  (4096ull*4)
#define IMGN_OFF  (SC_OFF + SC_BYTES)
#define F_BYTES   (128ull*768*4)
#define TXTN_OFF  (IMGN_OFF + F_BYTES)
#define MAX_OFF   (TXTN_OFF + F_BYTES)
#define MAX_BYTES (128ull*4096*4)
#define ACC_OFF   (MAX_OFF + MAX_BYTES)
#define CIDX_OFF  (ACC_OFF + 256ull)
#define NCC_OFF   (CIDX_OFF + 4096ull*4)
#define WS_NEED   (NCC_OFF + 256ull)

__device__ __forceinline__ void async_cp16(void* lds_p, const void* g) {
  __builtin_amdgcn_global_load_lds(
      (const __attribute__((address_space(1))) unsigned int*)g,
      (__attribute__((address_space(3))) unsigned int*)lds_p, 16, 0, 0);
}

__device__ __forceinline__ float neg_log_sigmoid(float x) {
  return (x > 0.f) ? log1pf(expf(-x)) : (log1pf(expf(x)) - x);
}

// monotone float<->int encoding for atomicMax on floats (no NaNs here)
__device__ __forceinline__ int encf(float f) {
  int i = __float_as_int(f);
  return i >= 0 ? i : (i ^ 0x7FFFFFFF);
}
__device__ __forceinline__ float decf(int e) {
  return __int_as_float(e >= 0 ? e : (e ^ 0x7FFFFFFF));
}

template<int VM>
__device__ __forceinline__ void vmwait() {
  asm volatile("s_waitcnt vmcnt(%0)" :: "n"(VM) : "memory");
}
__device__ __forceinline__ void blockbar() {
  asm volatile("" ::: "memory");
  __builtin_amdgcn_s_barrier();
  asm volatile("" ::: "memory");
}

// ---------------- column compaction ----------------
// cidx[j] = original concept row of compacted column j (valid j < tot),
// -1 for padding up to a multiple of 128. ncc[0] = padded total.
// Only valid concepts (w < counts[v]) enter the GEMM; invalid cols were
// masked out by the reference anyway.
__global__ void build_cidx(const int* __restrict__ counts, int* __restrict__ cidx,
                           int* __restrict__ ncc) {
  __shared__ int starts[129];
  int v = threadIdx.x;  // 0..127
  if (v == 0) {
    int run = 0;
    for (int i = 0; i < 128; ++i) { starts[i] = run; run += counts[i]; }
    starts[128] = run;
  }
  __syncthreads();
  int base = starts[v];
  int cnt = starts[v + 1] - base;
  for (int k = 0; k < cnt; ++k) cidx[base + k] = v * 32 + k;
  if (v == 0) {
    int tot = starts[128];
    int totp = (tot + 127) & ~127;
    for (int j = tot; j < totp; ++j) cidx[j] = -1;
    ncc[0] = totp;
  }
}

// ---------------- unified preprocessing kernel ----------------
__global__ void preproc_kernel(const float* __restrict__ tokp, char* __restrict__ outp,
                               float* __restrict__ srowp,
                               const float* __restrict__ tokc, char* __restrict__ outc,
                               float* __restrict__ srowc,
                               const float* __restrict__ imgf, float* __restrict__ imgn,
                               const float* __restrict__ txtf, float* __restrict__ txtn) {
  int bid = blockIdx.x;
  int t = threadIdx.x; // 0..191
  __shared__ float sbs[3], sba[3];

  const float* in;
  char* qout = nullptr;
  float* srow = nullptr;
  float* fout = nullptr;
  if (bid < MTOT) {
    in = tokp + (size_t)bid * DDIM; qout = outp + (size_t)bid * DDIM; srow = srowp + bid;
  } else if (bid < MTOT + NCOLS) {
    int r = bid - MTOT;
    in = tokc + (size_t)r * DDIM; qout = outc + (size_t)r * DDIM; srow = srowc + r;
  } else if (bid < MTOT + NCOLS + BATCH) {
    int r = bid - MTOT - NCOLS;
    in = imgf + (size_t)r * DDIM; fout = imgn + (size_t)r * DDIM;
  } else {
    int r = bid - MTOT - NCOLS - BATCH;
    in = txtf + (size_t)r * DDIM; fout = txtn + (size_t)r * DDIM;
  }

  float4 v = ((const float4*)in)[t];
  float ss = v.x*v.x + v.y*v.y + v.z*v.z + v.w*v.w;
  float am = fmaxf(fmaxf(fabsf(v.x), fabsf(v.y)), fmaxf(fabsf(v.z), fabsf(v.w)));
  #pragma unroll
  for (int o = 32; o; o >>= 1) {
    ss += __shfl_down(ss, o);
    am = fmaxf(am, __shfl_down(am, o));
  }
  if ((t & 63) == 0) { sbs[t >> 6] = ss; sba[t >> 6] = am; }
  __syncthreads();
  float tot = sbs[0] + sbs[1] + sbs[2];
  float amx = fmaxf(fmaxf(sba[0], sba[1]), fmaxf(sba[2], 1e-30f));

  if (qout) {
    float qs = 127.0f / amx;
    int qx = (int)rintf(v.x * qs), qy = (int)rintf(v.y * qs);
    int qz = (int)rintf(v.z * qs), qw = (int)rintf(v.w * qs);
    uint packed = (uint)(qx & 0xff) | ((uint)(qy & 0xff) << 8) |
                  ((uint)(qz & 0xff) << 16) | ((uint)(qw & 0xff) << 24);
    ((uint*)qout)[t] = packed;
    if (t == 0) srow[0] = amx / (127.0f * fmaxf(sqrtf(tot), 1e-12f));
  } else {
    float scale = 1.0f / fmaxf(sqrtf(tot), 1e-12f);
    ((float4*)fout)[t] = make_float4(v.x*scale, v.y*scale, v.z*scale, v.w*scale);
  }
}

// ---------------- RC GEMM (int8, compacted cols) + column max ----------------
// R6 structure (proven 111.4 us at full N): 256 threads, 4 waves (2Mx2N),
// wave tile 128x64, BK=64, 12 K-tiles, 3 LDS bufs x 24KB, quad-XOR swizzle,
// body {stage(t+2) | vmcnt(12) | bar | reads+32 MFMA | bar}.
// NEW: B columns are COMPACTED valid concepts via cidx gather; blocks whose
// column chunk is beyond the padded total exit immediately (~48% of blocks).
__global__ __launch_bounds__(256, 2)
void rc_gemm_max_kernel(const char* __restrict__ patches,
                        const char* __restrict__ concepts,
                        const float* __restrict__ sp,
                        const float* __restrict__ sc,
                        const int* __restrict__ cidx,
                        const int* __restrict__ ncc,
                        int* __restrict__ Max) {
  __shared__ __align__(16) char lds[3 * 24576];
  __shared__ float sp_lds[256];
  __shared__ float colmax[2][2][128];   // [wm][seg][col]

  const int bid0 = blockIdx.x;
  const int lin = (bid0 & 7) * 392 + (bid0 >> 3);  // bijective (3136 = 8*392)
  const int mt = lin >> 5;          // mt-major within XCD: B stays L2-hot
  const int bn = lin & 31;
  const int bcol = bn * BNC;        // compacted column base
  const int totp = __builtin_amdgcn_readfirstlane(ncc[0]);
  if (bcol >= totp) return;         // dead chunk (beyond valid concepts)

  const int tid = threadIdx.x;
  const int lane = tid & 63;
  const int wid = tid >> 6;
  const int wm = wid >> 1;   // 0..1
  const int wn = wid & 1;    // 0..1
  const int brow = mt * 256;

  const char* Ab = patches + (size_t)brow * DDIM;

  sp_lds[tid] = sp[brow + tid];

  // ds_read base offsets (quad-XOR swizzle; slot invariant across frag idx)
  const int arow = wm*128 + (lane & 15);
  const int aslot = (lane >> 4) ^ (((lane & 15) >> 1) & 3);
  const int a_base = arow*64 + aslot*16;
  const int bcl = wn*64 + (lane & 15);
  const int b_base = 16384 + bcl*64 + aslot*16;
  // staging voffset (element==byte for i8); slot invariant across k2 chunks
  const int r0 = tid >> 2;
  const int q0 = (tid & 3) ^ ((r0 >> 1) & 3);
  const int svoff = r0*DDIM + q0*16;

  // gathered B staging base pointers (row per compacted col, pad -> row 0)
  const int cr0 = cidx[bcol + (tid >> 2)];
  const int cr1 = cidx[bcol + 64 + (tid >> 2)];
  const char* bp0 = concepts + (size_t)(cr0 < 0 ? 0 : cr0) * DDIM + q0*16;
  const char* bp1 = concepts + (size_t)(cr1 < 0 ? 0 : cr1) * DDIM + q0*16;

  i32x4 acc[8][4];
  #pragma unroll
  for (int i = 0; i < 8; ++i)
    #pragma unroll
    for (int j = 0; j < 4; ++j) { i32x4 z = {0,0,0,0}; acc[i][j] = z; }

  // stage K-tile t into buffer: A 16KB (4 cp/thr), B 8KB (2 cp/thr, gathered)
  auto stage = [&](int t, int bufi) {
    char* dst = lds + bufi * 24576;
    const int kcol = t * 64;
    #pragma unroll
    for (int k2 = 0; k2 < 4; ++k2)
      async_cp16(dst + tid*16 + k2*4096, Ab + svoff + k2*(64*DDIM) + kcol);
    async_cp16(dst + 16384 + tid*16,        bp0 + kcol);
    async_cp16(dst + 16384 + tid*16 + 4096, bp1 + kcol);
  };

  auto compute = [&](int bufi) {
    const char* ab = lds + bufi * 24576;
    i32x4 a[8], b[4];
    #pragma unroll
    for (int i = 0; i < 8; ++i) a[i] = *(const i32x4*)(ab + a_base + i*1024);
    #pragma unroll
    for (int j = 0; j < 4; ++j) b[j] = *(const i32x4*)(ab + b_base + j*1024);
    __builtin_amdgcn_s_setprio(1);
    #pragma unroll
    for (int i = 0; i < 8; ++i)
      #pragma unroll
      for (int j = 0; j < 4; ++j)
        acc[i][j] = __builtin_amdgcn_mfma_i32_16x16x64_i8(a[i], b[j], acc[i][j], 0, 0, 0);
    __builtin_amdgcn_s_setprio(0);
  };

#define TILE(T, VMN, DOSTAGE)                                                 \
  {                                                                           \
    if (DOSTAGE) stage((T) + 2, ((T) + 2) % 3);                               \
    vmwait<VMN>();                                                            \
    blockbar();                                                               \
    compute((T) % 3);                                                         \
    blockbar();                                                               \
  }

  stage(0, 0);
  stage(1, 1);
  TILE(0, 12, 1)  TILE(1, 12, 1)  TILE(2, 12, 1)  TILE(3, 12, 1)
  TILE(4, 12, 1)  TILE(5, 12, 1)  TILE(6, 12, 1)  TILE(7, 12, 1)
  TILE(8, 12, 1)  TILE(9, 12, 1)  TILE(10, 6, 0)  TILE(11, 0, 0)
#undef TILE

  // epilogue: dequant + segmented column max (wave's 128 rows span <= 2 images)
  float cmax[4][2];
  #pragma unroll
  for (int j = 0; j < 4; ++j) { cmax[j][0] = -3e38f; cmax[j][1] = -3e38f; }
  float scv[4];
  #pragma unroll
  for (int j = 0; j < 4; ++j) {
    int oc = cidx[bcol + wn*64 + j*16 + (lane & 15)];
    scv[j] = sc[oc < 0 ? 0 : oc];
  }
  const int img0w = (brow + wm*128) / NPATCH;
  #pragma unroll
  for (int i = 0; i < 8; ++i) {
    #pragma unroll
    for (int e = 0; e < 4; ++e) {
      int rl = wm*128 + i*16 + (lane >> 4)*4 + e;
      float spv = sp_lds[rl];
      int seg = ((brow + rl) / NPATCH) - img0w;   // 0 or 1
      #pragma unroll
      for (int j = 0; j < 4; ++j) {
        float v = (float)acc[i][j][e] * spv * scv[j];
        cmax[j][0] = (seg == 0) ? fmaxf(cmax[j][0], v) : cmax[j][0];
        cmax[j][1] = (seg == 1) ? fmaxf(cmax[j][1], v) : cmax[j][1];
      }
    }
  }
  #pragma unroll
  for (int j = 0; j < 4; ++j) {
    #pragma unroll
    for (int s = 0; s < 2; ++s) {
      float v = cmax[j][s];
      v = fmaxf(v, __shfl_xor(v, 16));
      v = fmaxf(v, __shfl_xor(v, 32));
      cmax[j][s] = v;
    }
  }
  if (lane < 16) {
    #pragma unroll
    for (int j = 0; j < 4; ++j) {
      colmax[wm][0][wn*64 + j*16 + lane] = cmax[j][0];
      colmax[wm][1][wn*64 + j*16 + lane] = cmax[j][1];
    }
  }
  __syncthreads();
  {
    int w = tid >> 7;          // 0..1 (wm)
    int col = tid & 127;
    int oc = cidx[bcol + col];           // original Max column; -1 = padding
    if (oc >= 0) {
      int i0 = (brow + w*128) / NPATCH;
      int i1 = (brow + w*128 + 127) / NPATCH;
      atomicMax(&Max[(size_t)i0 * NCOLS + oc], encf(colmax[w][0][col]));
      if (i1 != i0) atomicMax(&Max[(size_t)i1 * NCOLS + oc], encf(colmax[w][1][col]));
    }
  }
}

// ---------------- fused losses ----------------
// blocks 0..127: IT loss row m; blocks 128..255: RC loss row m-128.
__global__ void loss_kernel(const float* __restrict__ imgn, const float* __restrict__ txtn,
                            const int* __restrict__ Max, const int* __restrict__ counts,
                            const float* __restrict__ sc, const float* __restrict__ bi,
                            float* __restrict__ acc) {
  int bid = blockIdx.x;
  int c = threadIdx.x;  // 128 threads
  float t = expf(fminf(fmaxf(sc[0], -10.f), 10.f));
  float val;
  int m;
  if (bid < BATCH) {
    m = bid;
    __shared__ __align__(16) float arow[DDIM];
    for (int k = c; k < DDIM; k += 128) arow[k] = imgn[(size_t)m * DDIM + k];
    __syncthreads();
    const float4* br = (const float4*)(txtn + (size_t)c * DDIM);
    const float4* ar = (const float4*)arow;
    float dot = 0.f;
    #pragma unroll 8
    for (int k = 0; k < DDIM/4; ++k) {
      float4 x = ar[k], y = br[k];
      dot += x.x*y.x + x.y*y.y + x.z*y.z + x.w*y.w;
    }
    float logit = fminf(fmaxf(t*dot + bi[0], -50.f), 50.f);
    val = neg_log_sigmoid((c == m) ? logit : -logit);
  } else {
    m = bid - BATCH;
    const int* row = Max + (size_t)m * NCOLS + (size_t)c * WCON;
    int cnt = counts[c];
    float s = 0.f;
    for (int w = 0; w < cnt; ++w) s += decf(row[w]);
    float S = s / (float)cnt;
    float logit = fminf(fmaxf(t*S + bi[0], -50.f), 50.f);
    val = neg_log_sigmoid((c == m) ? logit : -logit);
  }
  __shared__ float sb[2];
  #pragma unroll
  for (int o = 32; o; o >>= 1) val += __shfl_down(val, o);
  if ((c & 63) == 0) sb[c >> 6] = val;
  __syncthreads();
  if (c == 0) atomicAdd(acc + (bid < BATCH ? 0 : 1), sb[0] + sb[1]);
}

__global__ void finalize_kernel(const float* __restrict__ acc, float* __restrict__ out) {
  if (threadIdx.x == 0 && blockIdx.x == 0) {
    float it = acc[0] * (1.f / 16384.f);
    float rc = acc[1] * (1.f / 16384.f);
    out[0] = it + 0.5f * rc;
    out[1] = it;
    out[2] = rc;
  }
}

// ---------------- launch ----------------

extern "C" void kernel_launch(void* const* d_in, const int* in_sizes, int n_in,
                              void* d_out, int out_size, void* d_ws, size_t ws_size,
                              hipStream_t stream) {
  const float* image_features        = (const float*)d_in[0];
  const float* text_features         = (const float*)d_in[1];
  const float* image_token_features  = (const float*)d_in[2];
  const float* concept_text_features = (const float*)d_in[3];
  const int*   concept_counts        = (const int*)d_in[4];
  const float* logit_scale           = (const float*)d_in[5];
  const float* logit_bias            = (const float*)d_in[6];
  float* out = (float*)d_out;

  if (ws_size < WS_NEED) {
    hipMemsetAsync(d_out, 0, (size_t)out_size * sizeof(float), stream);
    return;
  }

  char* ws = (char*)d_ws;
  char*  patches_i8  = ws + PI8_OFF;
  char*  concepts_i8 = ws + CI8_OFF;
  float* sp          = (float*)(ws + SP_OFF);
  float* scq         = (float*)(ws + SC_OFF);
  float* imgn        = (float*)(ws + IMGN_OFF);
  float* txtn        = (float*)(ws + TXTN_OFF);
  int*   Maxbuf      = (int*)(ws + MAX_OFF);
  float* acc         = (float*)(ws + ACC_OFF);          // [0]=it, [1]=rc
  int*   cidx        = (int*)(ws + CIDX_OFF);
  int*   ncc         = (int*)(ws + NCC_OFF);

  hipMemsetAsync(ws + ACC_OFF, 0, 256, stream);
  hipMemsetAsync(Maxbuf, 0x80, MAX_BYTES, stream);      // decodes very negative

  build_cidx<<<1, 128, 0, stream>>>(concept_counts, cidx, ncc);
  preproc_kernel<<<MTOT + NCOLS + 2*BATCH, 192, 0, stream>>>(
      image_token_features, patches_i8, sp,
      concept_text_features, concepts_i8, scq,
      image_features, imgn, text_features, txtn);

  rc_gemm_max_kernel<<<NBLK, 256, 0, stream>>>(patches_i8, concepts_i8, sp, scq,
                                               cidx, ncc, Maxbuf);

  loss_kernel<<<2*BATCH, 128, 0, stream>>>(imgn, txtn, Maxbuf, concept_counts,
                                           logit_scale, logit_bias, acc);
  finalize_kernel<<<1, 64, 0, stream>>>(acc, out);
}

// Round 14
// 106.776 us; speedup vs baseline: 3.3942x; 1.1001x over previous
//
#include <hip/hip_runtime.h>
#include <hip/hip_bf16.h>
#include <cstdint>

using i32x4 = __attribute__((ext_vector_type(4))) int;

// Problem dims
#define BATCH   128
#define NPATCH  196
#define MTOT    25088   // 128*196, = 98*256 exactly
#define MT      98      // M-tiles of 256
#define DDIM    768
#define WCON    32
#define NCOLS   4096    // BATCH*WCON
#define BNC     128     // cols per block
#define NBN     32      // NCOLS/BNC
#define NT      12      // K-tiles of 64
#define NBLK    3136    // MT*NBN (fixed grid; excess blocks early-exit)

// preproc block ranges
#define PB_PAT  0
#define PB_CON  (MTOT)
#define PB_IMG  (MTOT + NCOLS)
#define PB_TXT  (MTOT + NCOLS + BATCH)
#define PB_MAX  (MTOT + NCOLS + 2*BATCH)       // 128 blocks: Maxbuf init
#define PB_CIDX (PB_MAX + 128)                 // 1 block: cidx build
#define PB_N    (PB_CIDX + 1)

// ws layout (bytes), each 256-aligned
#define PI8_OFF   0ull
#define PI8_BYTES ((size_t)MTOT*DDIM)
#define CI8_OFF   (PI8_OFF + PI8_BYTES)
#define CI8_BYTES (4096ull*DDIM)
#define SP_OFF    (CI8_OFF + CI8_BYTES)
#define SP_BYTES  ((size_t)MTOT*4)
#define SC_OFF    (SP_OFF + SP_BYTES)
#define SC_BYTES  (4096ull*4)
#define IMGN_OFF  (SC_OFF + SC_BYTES)
#define F_BYTES   (128ull*768*4)
#define TXTN_OFF  (IMGN_OFF + F_BYTES)
#define MAX_OFF   (TXTN_OFF + F_BYTES)
#define MAX_BYTES (128ull*4096*4)
#define PART_OFF  (MAX_OFF + MAX_BYTES)        // 256 floats (loss partials)
#define CIDX_OFF  (PART_OFF + 1024ull)
#define NCC_OFF   (CIDX_OFF + 4096ull*4)
#define WS_NEED   (NCC_OFF + 256ull)

__device__ __forceinline__ void async_cp16(void* lds_p, const void* g) {
  __builtin_amdgcn_global_load_lds(
      (const __attribute__((address_space(1))) unsigned int*)g,
      (__attribute__((address_space(3))) unsigned int*)lds_p, 16, 0, 0);
}

__device__ __forceinline__ float neg_log_sigmoid(float x) {
  return (x > 0.f) ? log1pf(expf(-x)) : (log1pf(expf(x)) - x);
}

// monotone float<->int encoding for atomicMax on floats (no NaNs here)
__device__ __forceinline__ int encf(float f) {
  int i = __float_as_int(f);
  return i >= 0 ? i : (i ^ 0x7FFFFFFF);
}
__device__ __forceinline__ float decf(int e) {
  return __int_as_float(e >= 0 ? e : (e ^ 0x7FFFFFFF));
}

template<int VM>
__device__ __forceinline__ void vmwait() {
  asm volatile("s_waitcnt vmcnt(%0)" :: "n"(VM) : "memory");
}
__device__ __forceinline__ void blockbar() {
  asm volatile("" ::: "memory");
  __builtin_amdgcn_s_barrier();
  asm volatile("" ::: "memory");
}

// ---------------- unified preprocessing (norms + quant + init + cidx) -------
__global__ void preproc_kernel(const float* __restrict__ tokp, char* __restrict__ outp,
                               float* __restrict__ srowp,
                               const float* __restrict__ tokc, char* __restrict__ outc,
                               float* __restrict__ srowc,
                               const float* __restrict__ imgf, float* __restrict__ imgn,
                               const float* __restrict__ txtf, float* __restrict__ txtn,
                               const int* __restrict__ counts,
                               int* __restrict__ Maxbuf,
                               int* __restrict__ cidx, int* __restrict__ ncc) {
  int bid = blockIdx.x;
  int t = threadIdx.x; // 0..191

  if (bid >= PB_MAX) {
    if (bid < PB_CIDX) {
      // Maxbuf init: 128 blocks x 4096 ints = 0x80808080 (very negative enc)
      int r = bid - PB_MAX;
      int* dst = Maxbuf + (size_t)r * 4096;
      for (int i = t; i < 4096; i += 192) dst[i] = 0x80808080;
    } else {
      // cidx build (parallel prefix over 128 counts in LDS)
      __shared__ int cls[128];
      __shared__ int stot;
      if (t < 128) cls[t] = counts[t];
      __syncthreads();
      if (t < 128) {
        int base = 0;
        for (int i = 0; i < t; ++i) base += cls[i];
        int cnt = cls[t];
        for (int k = 0; k < cnt; ++k) cidx[base + k] = t * 32 + k;
        if (t == 127) stot = base + cnt;
      }
      __syncthreads();
      if (t == 0) {
        int tot = stot;
        int totp = (tot + 127) & ~127;
        for (int j = tot; j < totp; ++j) cidx[j] = -1;
        ncc[0] = totp;
      }
    }
    return;
  }

  __shared__ float sbs[3], sba[3];
  const float* in;
  char* qout = nullptr;
  float* srow = nullptr;
  float* fout = nullptr;
  if (bid < PB_CON) {
    in = tokp + (size_t)bid * DDIM; qout = outp + (size_t)bid * DDIM; srow = srowp + bid;
  } else if (bid < PB_IMG) {
    int r = bid - PB_CON;
    if ((r & 31) >= counts[r >> 5]) return;    // invalid concept: never read
    in = tokc + (size_t)r * DDIM; qout = outc + (size_t)r * DDIM; srow = srowc + r;
  } else if (bid < PB_TXT) {
    int r = bid - PB_IMG;
    in = imgf + (size_t)r * DDIM; fout = imgn + (size_t)r * DDIM;
  } else {
    int r = bid - PB_TXT;
    in = txtf + (size_t)r * DDIM; fout = txtn + (size_t)r * DDIM;
  }

  float4 v = ((const float4*)in)[t];
  float ss = v.x*v.x + v.y*v.y + v.z*v.z + v.w*v.w;
  float am = fmaxf(fmaxf(fabsf(v.x), fabsf(v.y)), fmaxf(fabsf(v.z), fabsf(v.w)));
  #pragma unroll
  for (int o = 32; o; o >>= 1) {
    ss += __shfl_down(ss, o);
    am = fmaxf(am, __shfl_down(am, o));
  }
  if ((t & 63) == 0) { sbs[t >> 6] = ss; sba[t >> 6] = am; }
  __syncthreads();
  float tot = sbs[0] + sbs[1] + sbs[2];
  float amx = fmaxf(fmaxf(sba[0], sba[1]), fmaxf(sba[2], 1e-30f));

  if (qout) {
    float qs = 127.0f / amx;
    int qx = (int)rintf(v.x * qs), qy = (int)rintf(v.y * qs);
    int qz = (int)rintf(v.z * qs), qw = (int)rintf(v.w * qs);
    uint packed = (uint)(qx & 0xff) | ((uint)(qy & 0xff) << 8) |
                  ((uint)(qz & 0xff) << 16) | ((uint)(qw & 0xff) << 24);
    ((uint*)qout)[t] = packed;
    if (t == 0) srow[0] = amx / (127.0f * fmaxf(sqrtf(tot), 1e-12f));
  } else {
    float scale = 1.0f / fmaxf(sqrtf(tot), 1e-12f);
    ((float4*)fout)[t] = make_float4(v.x*scale, v.y*scale, v.z*scale, v.w*scale);
  }
}

// ---------------- RC GEMM (int8, compacted cols) + column max ----------------
// Verified R13 kernel (72.7 us): 256 threads, 4 waves (2Mx2N), wave 128x64,
// BK=64, 12 K-tiles, 3 LDS bufs x 24KB, quad-XOR swizzle, counted vmcnt(12).
// B columns gathered via cidx; blocks beyond padded total exit immediately.
__global__ __launch_bounds__(256, 2)
void rc_gemm_max_kernel(const char* __restrict__ patches,
                        const char* __restrict__ concepts,
                        const float* __restrict__ sp,
                        const float* __restrict__ sc,
                        const int* __restrict__ cidx,
                        const int* __restrict__ ncc,
                        int* __restrict__ Max) {
  __shared__ __align__(16) char lds[3 * 24576];
  __shared__ float sp_lds[256];
  __shared__ float colmax[2][2][128];   // [wm][seg][col]

  const int bid0 = blockIdx.x;
  const int lin = (bid0 & 7) * 392 + (bid0 >> 3);  // bijective (3136 = 8*392)
  const int mt = lin >> 5;          // mt-major within XCD: B stays L2-hot
  const int bn = lin & 31;
  const int bcol = bn * BNC;        // compacted column base
  const int totp = __builtin_amdgcn_readfirstlane(ncc[0]);
  if (bcol >= totp) return;         // dead chunk (beyond valid concepts)

  const int tid = threadIdx.x;
  const int lane = tid & 63;
  const int wid = tid >> 6;
  const int wm = wid >> 1;   // 0..1
  const int wn = wid & 1;    // 0..1
  const int brow = mt * 256;

  const char* Ab = patches + (size_t)brow * DDIM;

  sp_lds[tid] = sp[brow + tid];

  // ds_read base offsets (quad-XOR swizzle; slot invariant across frag idx)
  const int arow = wm*128 + (lane & 15);
  const int aslot = (lane >> 4) ^ (((lane & 15) >> 1) & 3);
  const int a_base = arow*64 + aslot*16;
  const int bcl = wn*64 + (lane & 15);
  const int b_base = 16384 + bcl*64 + aslot*16;
  // staging voffset (element==byte for i8); slot invariant across k2 chunks
  const int r0 = tid >> 2;
  const int q0 = (tid & 3) ^ ((r0 >> 1) & 3);
  const int svoff = r0*DDIM + q0*16;

  // gathered B staging base pointers (row per compacted col, pad -> row 0)
  const int cr0 = cidx[bcol + (tid >> 2)];
  const int cr1 = cidx[bcol + 64 + (tid >> 2)];
  const char* bp0 = concepts + (size_t)(cr0 < 0 ? 0 : cr0) * DDIM + q0*16;
  const char* bp1 = concepts + (size_t)(cr1 < 0 ? 0 : cr1) * DDIM + q0*16;

  i32x4 acc[8][4];
  #pragma unroll
  for (int i = 0; i < 8; ++i)
    #pragma unroll
    for (int j = 0; j < 4; ++j) { i32x4 z = {0,0,0,0}; acc[i][j] = z; }

  // stage K-tile t into buffer: A 16KB (4 cp/thr), B 8KB (2 cp/thr, gathered)
  auto stage = [&](int t, int bufi) {
    char* dst = lds + bufi * 24576;
    const int kcol = t * 64;
    #pragma unroll
    for (int k2 = 0; k2 < 4; ++k2)
      async_cp16(dst + tid*16 + k2*4096, Ab + svoff + k2*(64*DDIM) + kcol);
    async_cp16(dst + 16384 + tid*16,        bp0 + kcol);
    async_cp16(dst + 16384 + tid*16 + 4096, bp1 + kcol);
  };

  auto compute = [&](int bufi) {
    const char* ab = lds + bufi * 24576;
    i32x4 a[8], b[4];
    #pragma unroll
    for (int i = 0; i < 8; ++i) a[i] = *(const i32x4*)(ab + a_base + i*1024);
    #pragma unroll
    for (int j = 0; j < 4; ++j) b[j] = *(const i32x4*)(ab + b_base + j*1024);
    __builtin_amdgcn_s_setprio(1);
    #pragma unroll
    for (int i = 0; i < 8; ++i)
      #pragma unroll
      for (int j = 0; j < 4; ++j)
        acc[i][j] = __builtin_amdgcn_mfma_i32_16x16x64_i8(a[i], b[j], acc[i][j], 0, 0, 0);
    __builtin_amdgcn_s_setprio(0);
  };

#define TILE(T, VMN, DOSTAGE)                                                 \
  {                                                                           \
    if (DOSTAGE) stage((T) + 2, ((T) + 2) % 3);                               \
    vmwait<VMN>();                                                            \
    blockbar();                                                               \
    compute((T) % 3);                                                         \
    blockbar();                                                               \
  }

  stage(0, 0);
  stage(1, 1);
  TILE(0, 12, 1)  TILE(1, 12, 1)  TILE(2, 12, 1)  TILE(3, 12, 1)
  TILE(4, 12, 1)  TILE(5, 12, 1)  TILE(6, 12, 1)  TILE(7, 12, 1)
  TILE(8, 12, 1)  TILE(9, 12, 1)  TILE(10, 6, 0)  TILE(11, 0, 0)
#undef TILE

  // epilogue: dequant + segmented column max (wave's 128 rows span <= 2 images)
  float cmax[4][2];
  #pragma unroll
  for (int j = 0; j < 4; ++j) { cmax[j][0] = -3e38f; cmax[j][1] = -3e38f; }
  float scv[4];
  #pragma unroll
  for (int j = 0; j < 4; ++j) {
    int oc = cidx[bcol + wn*64 + j*16 + (lane & 15)];
    scv[j] = sc[oc < 0 ? 0 : oc];
  }
  const int img0w = (brow + wm*128) / NPATCH;
  #pragma unroll
  for (int i = 0; i < 8; ++i) {
    #pragma unroll
    for (int e = 0; e < 4; ++e) {
      int rl = wm*128 + i*16 + (lane >> 4)*4 + e;
      float spv = sp_lds[rl];
      int seg = ((brow + rl) / NPATCH) - img0w;   // 0 or 1
      #pragma unroll
      for (int j = 0; j < 4; ++j) {
        float v = (float)acc[i][j][e] * spv * scv[j];
        cmax[j][0] = (seg == 0) ? fmaxf(cmax[j][0], v) : cmax[j][0];
        cmax[j][1] = (seg == 1) ? fmaxf(cmax[j][1], v) : cmax[j][1];
      }
    }
  }
  #pragma unroll
  for (int j = 0; j < 4; ++j) {
    #pragma unroll
    for (int s = 0; s < 2; ++s) {
      float v = cmax[j][s];
      v = fmaxf(v, __shfl_xor(v, 16));
      v = fmaxf(v, __shfl_xor(v, 32));
      cmax[j][s] = v;
    }
  }
  if (lane < 16) {
    #pragma unroll
    for (int j = 0; j < 4; ++j) {
      colmax[wm][0][wn*64 + j*16 + lane] = cmax[j][0];
      colmax[wm][1][wn*64 + j*16 + lane] = cmax[j][1];
    }
  }
  __syncthreads();
  {
    int w = tid >> 7;          // 0..1 (wm)
    int col = tid & 127;
    int oc = cidx[bcol + col];           // original Max column; -1 = padding
    if (oc >= 0) {
      int i0 = (brow + w*128) / NPATCH;
      int i1 = (brow + w*128 + 127) / NPATCH;
      atomicMax(&Max[(size_t)i0 * NCOLS + oc], encf(colmax[w][0][col]));
      if (i1 != i0) atomicMax(&Max[(size_t)i1 * NCOLS + oc], encf(colmax[w][1][col]));
    }
  }
}

// ---------------- fused losses (per-block partials, no atomics) -------------
// blocks 0..127: IT loss row m; blocks 128..255: RC loss row m-128.
__global__ void loss_kernel(const float* __restrict__ imgn, const float* __restrict__ txtn,
                            const int* __restrict__ Max, const int* __restrict__ counts,
                            const float* __restrict__ sc, const float* __restrict__ bi,
                            float* __restrict__ part) {
  int bid = blockIdx.x;
  int c = threadIdx.x;  // 128 threads
  float t = expf(fminf(fmaxf(sc[0], -10.f), 10.f));
  float val;
  int m;
  if (bid < BATCH) {
    m = bid;
    __shared__ __align__(16) float arow[DDIM];
    for (int k = c; k < DDIM; k += 128) arow[k] = imgn[(size_t)m * DDIM + k];
    __syncthreads();
    const float4* br = (const float4*)(txtn + (size_t)c * DDIM);
    const float4* ar = (const float4*)arow;
    float dot = 0.f;
    #pragma unroll 8
    for (int k = 0; k < DDIM/4; ++k) {
      float4 x = ar[k], y = br[k];
      dot += x.x*y.x + x.y*y.y + x.z*y.z + x.w*y.w;
    }
    float logit = fminf(fmaxf(t*dot + bi[0], -50.f), 50.f);
    val = neg_log_sigmoid((c == m) ? logit : -logit);
  } else {
    m = bid - BATCH;
    const int* row = Max + (size_t)m * NCOLS + (size_t)c * WCON;
    int cnt = counts[c];
    float s = 0.f;
    for (int w = 0; w < cnt; ++w) s += decf(row[w]);
    float S = s / (float)cnt;
    float logit = fminf(fmaxf(t*S + bi[0], -50.f), 50.f);
    val = neg_log_sigmoid((c == m) ? logit : -logit);
  }
  __shared__ float sb[2];
  #pragma unroll
  for (int o = 32; o; o >>= 1) val += __shfl_down(val, o);
  if ((c & 63) == 0) sb[c >> 6] = val;
  __syncthreads();
  if (c == 0) part[bid] = sb[0] + sb[1];
}

__global__ void finalize_kernel(const float* __restrict__ part, float* __restrict__ out) {
  int t = threadIdx.x;   // 256 threads
  float v = part[t];
  __shared__ float sb[4];
  #pragma unroll
  for (int o = 32; o; o >>= 1) v += __shfl_down(v, o);
  if ((t & 63) == 0) sb[t >> 6] = v;
  __syncthreads();
  if (t == 0) {
    float it = (sb[0] + sb[1]) * (1.f / 16384.f);
    float rc = (sb[2] + sb[3]) * (1.f / 16384.f);
    out[0] = it + 0.5f * rc;
    out[1] = it;
    out[2] = rc;
  }
}

// ---------------- launch ----------------

extern "C" void kernel_launch(void* const* d_in, const int* in_sizes, int n_in,
                              void* d_out, int out_size, void* d_ws, size_t ws_size,
                              hipStream_t stream) {
  const float* image_features        = (const float*)d_in[0];
  const float* text_features         = (const float*)d_in[1];
  const float* image_token_features  = (const float*)d_in[2];
  const float* concept_text_features = (const float*)d_in[3];
  const int*   concept_counts        = (const int*)d_in[4];
  const float* logit_scale           = (const float*)d_in[5];
  const float* logit_bias            = (const float*)d_in[6];
  float* out = (float*)d_out;

  if (ws_size < WS_NEED) {
    hipMemsetAsync(d_out, 0, (size_t)out_size * sizeof(float), stream);
    return;
  }

  char* ws = (char*)d_ws;
  char*  patches_i8  = ws + PI8_OFF;
  char*  concepts_i8 = ws + CI8_OFF;
  float* sp          = (float*)(ws + SP_OFF);
  float* scq         = (float*)(ws + SC_OFF);
  float* imgn        = (float*)(ws + IMGN_OFF);
  float* txtn        = (float*)(ws + TXTN_OFF);
  int*   Maxbuf      = (int*)(ws + MAX_OFF);
  float* part        = (float*)(ws + PART_OFF);
  int*   cidx        = (int*)(ws + CIDX_OFF);
  int*   ncc         = (int*)(ws + NCC_OFF);

  preproc_kernel<<<PB_N, 192, 0, stream>>>(
      image_token_features, patches_i8, sp,
      concept_text_features, concepts_i8, scq,
      image_features, imgn, text_features, txtn,
      concept_counts, Maxbuf, cidx, ncc);

  rc_gemm_max_kernel<<<NBLK, 256, 0, stream>>>(patches_i8, concepts_i8, sp, scq,
                                               cidx, ncc, Maxbuf);

  loss_kernel<<<2*BATCH, 128, 0, stream>>>(imgn, txtn, Maxbuf, concept_counts,
                                           logit_scale, logit_bias, part);
  finalize_kernel<<<1, 256, 0, stream>>>(part, out);
}

// Round 15
// 105.597 us; speedup vs baseline: 3.4321x; 1.0112x over previous
//
#include <hip/hip_runtime.h>
#include <hip/hip_bf16.h>
#include <cstdint>

using i32x4 = __attribute__((ext_vector_type(4))) int;

// Problem dims
#define BATCH   128
#define NPATCH  196
#define MTOT    25088   // 128*196, = 98*256 exactly
#define MT      98      // M-tiles of 256
#define DDIM    768
#define WCON    32
#define NCOLS   4096    // BATCH*WCON
#define BNC     128     // cols per block
#define NBN     32      // NCOLS/BNC
#define NT      12      // K-tiles of 64
#define NBLK    3136    // MT*NBN (fixed grid; excess blocks early-exit)

// preproc block ranges (2 rows per block for patch/concept segments)
#define PB_PAT  0
#define NPAT2   (MTOT/2)                       // 12544
#define PB_CON  (NPAT2)
#define NCON2   (NCOLS/2)                      // 2048
#define PB_IMG  (PB_CON + NCON2)
#define PB_TXT  (PB_IMG + BATCH)
#define PB_MAX  (PB_TXT + BATCH)               // 64 blocks: Maxbuf init (int4)
#define PB_CIDX (PB_MAX + 64)                  // 1 block: cidx build
#define PB_N    (PB_CIDX + 1)

// ws layout (bytes), each 256-aligned
#define PI8_OFF   0ull
#define PI8_BYTES ((size_t)MTOT*DDIM)
#define CI8_OFF   (PI8_OFF + PI8_BYTES)
#define CI8_BYTES (4096ull*DDIM)
#define SP_OFF    (CI8_OFF + CI8_BYTES)
#define SP_BYTES  ((size_t)MTOT*4)
#define SC_OFF    (SP_OFF + SP_BYTES)
#define SC_BYTES  (4096ull*4)
#define IMGN_OFF  (SC_OFF + SC_BYTES)
#define F_BYTES   (128ull*768*4)
#define TXTN_OFF  (IMGN_OFF + F_BYTES)
#define MAX_OFF   (TXTN_OFF + F_BYTES)
#define MAX_BYTES (128ull*4096*4)
#define PART_OFF  (MAX_OFF + MAX_BYTES)        // 256 floats (loss partials)
#define CIDX_OFF  (PART_OFF + 1024ull)
#define NCC_OFF   (CIDX_OFF + 4096ull*4)
#define WS_NEED   (NCC_OFF + 256ull)

__device__ __forceinline__ void async_cp16(void* lds_p, const void* g) {
  __builtin_amdgcn_global_load_lds(
      (const __attribute__((address_space(1))) unsigned int*)g,
      (__attribute__((address_space(3))) unsigned int*)lds_p, 16, 0, 0);
}

__device__ __forceinline__ float neg_log_sigmoid(float x) {
  return (x > 0.f) ? log1pf(expf(-x)) : (log1pf(expf(x)) - x);
}

// monotone float<->int encoding for atomicMax on floats (no NaNs here)
__device__ __forceinline__ int encf(float f) {
  int i = __float_as_int(f);
  return i >= 0 ? i : (i ^ 0x7FFFFFFF);
}
__device__ __forceinline__ float decf(int e) {
  return __int_as_float(e >= 0 ? e : (e ^ 0x7FFFFFFF));
}

template<int VM>
__device__ __forceinline__ void vmwait() {
  asm volatile("s_waitcnt vmcnt(%0)" :: "n"(VM) : "memory");
}
__device__ __forceinline__ void blockbar() {
  asm volatile("" ::: "memory");
  __builtin_amdgcn_s_barrier();
  asm volatile("" ::: "memory");
}

// ---------------- unified preprocessing (norms + quant + init + cidx) -------
// Patch/concept segments: TWO rows per block (2 independent 16B loads/thread
// in flight -> latency-hiding), per-row predicated handling for concepts.
__global__ void preproc_kernel(const float* __restrict__ tokp, char* __restrict__ outp,
                               float* __restrict__ srowp,
                               const float* __restrict__ tokc, char* __restrict__ outc,
                               float* __restrict__ srowc,
                               const float* __restrict__ imgf, float* __restrict__ imgn,
                               const float* __restrict__ txtf, float* __restrict__ txtn,
                               const int* __restrict__ counts,
                               int* __restrict__ Maxbuf,
                               int* __restrict__ cidx, int* __restrict__ ncc) {
  int bid = blockIdx.x;
  int t = threadIdx.x; // 0..191

  if (bid >= PB_MAX) {
    if (bid < PB_CIDX) {
      // Maxbuf init: 64 blocks x 8192 ints, int4 stores
      int r = bid - PB_MAX;
      int4* dst = (int4*)(Maxbuf + (size_t)r * 8192);
      int4 pat = make_int4(0x80808080, 0x80808080, 0x80808080, 0x80808080);
      #pragma unroll
      for (int i = 0; i < 11; ++i) {
        int idx = t + i*192;
        if (idx < 2048) dst[idx] = pat;
      }
    } else {
      // cidx build
      __shared__ int cls[128];
      __shared__ int stot;
      if (t < 128) cls[t] = counts[t];
      __syncthreads();
      if (t < 128) {
        int base = 0;
        for (int i = 0; i < t; ++i) base += cls[i];
        int cnt = cls[t];
        for (int k = 0; k < cnt; ++k) cidx[base + k] = t * 32 + k;
        if (t == 127) stot = base + cnt;
      }
      __syncthreads();
      if (t == 0) {
        int tot = stot;
        int totp = (tot + 127) & ~127;
        for (int j = tot; j < totp; ++j) cidx[j] = -1;
        ncc[0] = totp;
      }
    }
    return;
  }

  if (bid >= PB_IMG) {
    // single-row f32 normalize (cls features)
    const float* in;
    float* fout;
    if (bid < PB_TXT) {
      int r = bid - PB_IMG;
      in = imgf + (size_t)r * DDIM; fout = imgn + (size_t)r * DDIM;
    } else {
      int r = bid - PB_TXT;
      in = txtf + (size_t)r * DDIM; fout = txtn + (size_t)r * DDIM;
    }
    __shared__ float sbs[3];
    float4 v = ((const float4*)in)[t];
    float ss = v.x*v.x + v.y*v.y + v.z*v.z + v.w*v.w;
    #pragma unroll
    for (int o = 32; o; o >>= 1) ss += __shfl_down(ss, o);
    if ((t & 63) == 0) sbs[t >> 6] = ss;
    __syncthreads();
    float tot = sbs[0] + sbs[1] + sbs[2];
    float scale = 1.0f / fmaxf(sqrtf(tot), 1e-12f);
    ((float4*)fout)[t] = make_float4(v.x*scale, v.y*scale, v.z*scale, v.w*scale);
    return;
  }

  // two-row quantize segments
  const float *inA, *inB;
  char *qoutA, *qoutB;
  float *srowA, *srowB;
  bool validA = true, validB = true;
  if (bid < PB_CON) {
    int r = bid * 2;              // patch rows r, r+1
    inA = tokp + (size_t)r * DDIM;       inB = inA + DDIM;
    qoutA = outp + (size_t)r * DDIM;     qoutB = qoutA + DDIM;
    srowA = srowp + r;                   srowB = srowA + 1;
  } else {
    int r = (bid - PB_CON) * 2;   // concept rows r, r+1 (same group)
    int cnt = counts[r >> 5];
    validA = (r & 31) < cnt;
    validB = ((r & 31) + 1) < cnt;
    if (!validA && !validB) return;
    inA = tokc + (size_t)r * DDIM;       inB = inA + DDIM;
    qoutA = outc + (size_t)r * DDIM;     qoutB = qoutA + DDIM;
    srowA = srowc + r;                   srowB = srowA + 1;
  }

  __shared__ float sA[3], aA[3], sB[3], aB[3];
  float4 vA = validA ? ((const float4*)inA)[t] : make_float4(0,0,0,0);
  float4 vB = validB ? ((const float4*)inB)[t] : make_float4(0,0,0,0);
  float ssA = vA.x*vA.x + vA.y*vA.y + vA.z*vA.z + vA.w*vA.w;
  float ssB = vB.x*vB.x + vB.y*vB.y + vB.z*vB.z + vB.w*vB.w;
  float amA = fmaxf(fmaxf(fabsf(vA.x), fabsf(vA.y)), fmaxf(fabsf(vA.z), fabsf(vA.w)));
  float amB = fmaxf(fmaxf(fabsf(vB.x), fabsf(vB.y)), fmaxf(fabsf(vB.z), fabsf(vB.w)));
  #pragma unroll
  for (int o = 32; o; o >>= 1) {
    ssA += __shfl_down(ssA, o);  amA = fmaxf(amA, __shfl_down(amA, o));
    ssB += __shfl_down(ssB, o);  amB = fmaxf(amB, __shfl_down(amB, o));
  }
  if ((t & 63) == 0) {
    sA[t >> 6] = ssA; aA[t >> 6] = amA;
    sB[t >> 6] = ssB; aB[t >> 6] = amB;
  }
  __syncthreads();
  float totA = sA[0] + sA[1] + sA[2];
  float totB = sB[0] + sB[1] + sB[2];
  float amxA = fmaxf(fmaxf(aA[0], aA[1]), fmaxf(aA[2], 1e-30f));
  float amxB = fmaxf(fmaxf(aB[0], aB[1]), fmaxf(aB[2], 1e-30f));

  if (validA) {
    float qs = 127.0f / amxA;
    int qx = (int)rintf(vA.x * qs), qy = (int)rintf(vA.y * qs);
    int qz = (int)rintf(vA.z * qs), qw = (int)rintf(vA.w * qs);
    ((uint*)qoutA)[t] = (uint)(qx & 0xff) | ((uint)(qy & 0xff) << 8) |
                        ((uint)(qz & 0xff) << 16) | ((uint)(qw & 0xff) << 24);
    if (t == 0) srowA[0] = amxA / (127.0f * fmaxf(sqrtf(totA), 1e-12f));
  }
  if (validB) {
    float qs = 127.0f / amxB;
    int qx = (int)rintf(vB.x * qs), qy = (int)rintf(vB.y * qs);
    int qz = (int)rintf(vB.z * qs), qw = (int)rintf(vB.w * qs);
    ((uint*)qoutB)[t] = (uint)(qx & 0xff) | ((uint)(qy & 0xff) << 8) |
                        ((uint)(qz & 0xff) << 16) | ((uint)(qw & 0xff) << 24);
    if (t == 0) srowB[0] = amxB / (127.0f * fmaxf(sqrtf(totB), 1e-12f));
  }
}

// ---------------- RC GEMM (int8, compacted cols) + column max ----------------
// FROZEN R13 kernel (72.7 us): 256 threads, 4 waves (2Mx2N), wave 128x64,
// BK=64, 12 K-tiles, 3 LDS bufs x 24KB, quad-XOR swizzle, counted vmcnt(12).
// B columns gathered via cidx; blocks beyond padded total exit immediately.
__global__ __launch_bounds__(256, 2)
void rc_gemm_max_kernel(const char* __restrict__ patches,
                        const char* __restrict__ concepts,
                        const float* __restrict__ sp,
                        const float* __restrict__ sc,
                        const int* __restrict__ cidx,
                        const int* __restrict__ ncc,
                        int* __restrict__ Max) {
  __shared__ __align__(16) char lds[3 * 24576];
  __shared__ float sp_lds[256];
  __shared__ float colmax[2][2][128];   // [wm][seg][col]

  const int bid0 = blockIdx.x;
  const int lin = (bid0 & 7) * 392 + (bid0 >> 3);  // bijective (3136 = 8*392)
  const int mt = lin >> 5;          // mt-major within XCD: B stays L2-hot
  const int bn = lin & 31;
  const int bcol = bn * BNC;        // compacted column base
  const int totp = __builtin_amdgcn_readfirstlane(ncc[0]);
  if (bcol >= totp) return;         // dead chunk (beyond valid concepts)

  const int tid = threadIdx.x;
  const int lane = tid & 63;
  const int wid = tid >> 6;
  const int wm = wid >> 1;   // 0..1
  const int wn = wid & 1;    // 0..1
  const int brow = mt * 256;

  const char* Ab = patches + (size_t)brow * DDIM;

  sp_lds[tid] = sp[brow + tid];

  // ds_read base offsets (quad-XOR swizzle; slot invariant across frag idx)
  const int arow = wm*128 + (lane & 15);
  const int aslot = (lane >> 4) ^ (((lane & 15) >> 1) & 3);
  const int a_base = arow*64 + aslot*16;
  const int bcl = wn*64 + (lane & 15);
  const int b_base = 16384 + bcl*64 + aslot*16;
  // staging voffset (element==byte for i8); slot invariant across k2 chunks
  const int r0 = tid >> 2;
  const int q0 = (tid & 3) ^ ((r0 >> 1) & 3);
  const int svoff = r0*DDIM + q0*16;

  // gathered B staging base pointers (row per compacted col, pad -> row 0)
  const int cr0 = cidx[bcol + (tid >> 2)];
  const int cr1 = cidx[bcol + 64 + (tid >> 2)];
  const char* bp0 = concepts + (size_t)(cr0 < 0 ? 0 : cr0) * DDIM + q0*16;
  const char* bp1 = concepts + (size_t)(cr1 < 0 ? 0 : cr1) * DDIM + q0*16;

  i32x4 acc[8][4];
  #pragma unroll
  for (int i = 0; i < 8; ++i)
    #pragma unroll
    for (int j = 0; j < 4; ++j) { i32x4 z = {0,0,0,0}; acc[i][j] = z; }

  // stage K-tile t into buffer: A 16KB (4 cp/thr), B 8KB (2 cp/thr, gathered)
  auto stage = [&](int t, int bufi) {
    char* dst = lds + bufi * 24576;
    const int kcol = t * 64;
    #pragma unroll
    for (int k2 = 0; k2 < 4; ++k2)
      async_cp16(dst + tid*16 + k2*4096, Ab + svoff + k2*(64*DDIM) + kcol);
    async_cp16(dst + 16384 + tid*16,        bp0 + kcol);
    async_cp16(dst + 16384 + tid*16 + 4096, bp1 + kcol);
  };

  auto compute = [&](int bufi) {
    const char* ab = lds + bufi * 24576;
    i32x4 a[8], b[4];
    #pragma unroll
    for (int i = 0; i < 8; ++i) a[i] = *(const i32x4*)(ab + a_base + i*1024);
    #pragma unroll
    for (int j = 0; j < 4; ++j) b[j] = *(const i32x4*)(ab + b_base + j*1024);
    __builtin_amdgcn_s_setprio(1);
    #pragma unroll
    for (int i = 0; i < 8; ++i)
      #pragma unroll
      for (int j = 0; j < 4; ++j)
        acc[i][j] = __builtin_amdgcn_mfma_i32_16x16x64_i8(a[i], b[j], acc[i][j], 0, 0, 0);
    __builtin_amdgcn_s_setprio(0);
  };

#define TILE(T, VMN, DOSTAGE)                                                 \
  {                                                                           \
    if (DOSTAGE) stage((T) + 2, ((T) + 2) % 3);                               \
    vmwait<VMN>();                                                            \
    blockbar();                                                               \
    compute((T) % 3);                                                         \
    blockbar();                                                               \
  }

  stage(0, 0);
  stage(1, 1);
  TILE(0, 12, 1)  TILE(1, 12, 1)  TILE(2, 12, 1)  TILE(3, 12, 1)
  TILE(4, 12, 1)  TILE(5, 12, 1)  TILE(6, 12, 1)  TILE(7, 12, 1)
  TILE(8, 12, 1)  TILE(9, 12, 1)  TILE(10, 6, 0)  TILE(11, 0, 0)
#undef TILE

  // epilogue: dequant + segmented column max (wave's 128 rows span <= 2 images)
  float cmax[4][2];
  #pragma unroll
  for (int j = 0; j < 4; ++j) { cmax[j][0] = -3e38f; cmax[j][1] = -3e38f; }
  float scv[4];
  #pragma unroll
  for (int j = 0; j < 4; ++j) {
    int oc = cidx[bcol + wn*64 + j*16 + (lane & 15)];
    scv[j] = sc[oc < 0 ? 0 : oc];
  }
  const int img0w = (brow + wm*128) / NPATCH;
  #pragma unroll
  for (int i = 0; i < 8; ++i) {
    #pragma unroll
    for (int e = 0; e < 4; ++e) {
      int rl = wm*128 + i*16 + (lane >> 4)*4 + e;
      float spv = sp_lds[rl];
      int seg = ((brow + rl) / NPATCH) - img0w;   // 0 or 1
      #pragma unroll
      for (int j = 0; j < 4; ++j) {
        float v = (float)acc[i][j][e] * spv * scv[j];
        cmax[j][0] = (seg == 0) ? fmaxf(cmax[j][0], v) : cmax[j][0];
        cmax[j][1] = (seg == 1) ? fmaxf(cmax[j][1], v) : cmax[j][1];
      }
    }
  }
  #pragma unroll
  for (int j = 0; j < 4; ++j) {
    #pragma unroll
    for (int s = 0; s < 2; ++s) {
      float v = cmax[j][s];
      v = fmaxf(v, __shfl_xor(v, 16));
      v = fmaxf(v, __shfl_xor(v, 32));
      cmax[j][s] = v;
    }
  }
  if (lane < 16) {
    #pragma unroll
    for (int j = 0; j < 4; ++j) {
      colmax[wm][0][wn*64 + j*16 + lane] = cmax[j][0];
      colmax[wm][1][wn*64 + j*16 + lane] = cmax[j][1];
    }
  }
  __syncthreads();
  {
    int w = tid >> 7;          // 0..1 (wm)
    int col = tid & 127;
    int oc = cidx[bcol + col];           // original Max column; -1 = padding
    if (oc >= 0) {
      int i0 = (brow + w*128) / NPATCH;
      int i1 = (brow + w*128 + 127) / NPATCH;
      atomicMax(&Max[(size_t)i0 * NCOLS + oc], encf(colmax[w][0][col]));
      if (i1 != i0) atomicMax(&Max[(size_t)i1 * NCOLS + oc], encf(colmax[w][1][col]));
    }
  }
}

// ---------------- fused losses (per-block partials, no atomics) -------------
__global__ void loss_kernel(const float* __restrict__ imgn, const float* __restrict__ txtn,
                            const int* __restrict__ Max, const int* __restrict__ counts,
                            const float* __restrict__ sc, const float* __restrict__ bi,
                            float* __restrict__ part) {
  int bid = blockIdx.x;
  int c = threadIdx.x;  // 128 threads
  float t = expf(fminf(fmaxf(sc[0], -10.f), 10.f));
  float val;
  int m;
  if (bid < BATCH) {
    m = bid;
    __shared__ __align__(16) float arow[DDIM];
    for (int k = c; k < DDIM; k += 128) arow[k] = imgn[(size_t)m * DDIM + k];
    __syncthreads();
    const float4* br = (const float4*)(txtn + (size_t)c * DDIM);
    const float4* ar = (const float4*)arow;
    float dot = 0.f;
    #pragma unroll 8
    for (int k = 0; k < DDIM/4; ++k) {
      float4 x = ar[k], y = br[k];
      dot += x.x*y.x + x.y*y.y + x.z*y.z + x.w*y.w;
    }
    float logit = fminf(fmaxf(t*dot + bi[0], -50.f), 50.f);
    val = neg_log_sigmoid((c == m) ? logit : -logit);
  } else {
    m = bid - BATCH;
    const int* row = Max + (size_t)m * NCOLS + (size_t)c * WCON;
    int cnt = counts[c];
    float s = 0.f;
    for (int w = 0; w < cnt; ++w) s += decf(row[w]);
    float S = s / (float)cnt;
    float logit = fminf(fmaxf(t*S + bi[0], -50.f), 50.f);
    val = neg_log_sigmoid((c == m) ? logit : -logit);
  }
  __shared__ float sb[2];
  #pragma unroll
  for (int o = 32; o; o >>= 1) val += __shfl_down(val, o);
  if ((c & 63) == 0) sb[c >> 6] = val;
  __syncthreads();
  if (c == 0) part[bid] = sb[0] + sb[1];
}

__global__ void finalize_kernel(const float* __restrict__ part, float* __restrict__ out) {
  int t = threadIdx.x;   // 256 threads
  float v = part[t];
  __shared__ float sb[4];
  #pragma unroll
  for (int o = 32; o; o >>= 1) v += __shfl_down(v, o);
  if ((t & 63) == 0) sb[t >> 6] = v;
  __syncthreads();
  if (t == 0) {
    float it = (sb[0] + sb[1]) * (1.f / 16384.f);
    float rc = (sb[2] + sb[3]) * (1.f / 16384.f);
    out[0] = it + 0.5f * rc;
    out[1] = it;
    out[2] = rc;
  }
}

// ---------------- launch ----------------

extern "C" void kernel_launch(void* const* d_in, const int* in_sizes, int n_in,
                              void* d_out, int out_size, void* d_ws, size_t ws_size,
                              hipStream_t stream) {
  const float* image_features        = (const float*)d_in[0];
  const float* text_features         = (const float*)d_in[1];
  const float* image_token_features  = (const float*)d_in[2];
  const float* concept_text_features = (const float*)d_in[3];
  const int*   concept_counts        = (const int*)d_in[4];
  const float* logit_scale           = (const float*)d_in[5];
  const float* logit_bias            = (const float*)d_in[6];
  float* out = (float*)d_out;

  if (ws_size < WS_NEED) {
    hipMemsetAsync(d_out, 0, (size_t)out_size * sizeof(float), stream);
    return;
  }

  char* ws = (char*)d_ws;
  char*  patches_i8  = ws + PI8_OFF;
  char*  concepts_i8 = ws + CI8_OFF;
  float* sp          = (float*)(ws + SP_OFF);
  float* scq         = (float*)(ws + SC_OFF);
  float* imgn        = (float*)(ws + IMGN_OFF);
  float* txtn        = (float*)(ws + TXTN_OFF);
  int*   Maxbuf      = (int*)(ws + MAX_OFF);
  float* part        = (float*)(ws + PART_OFF);
  int*   cidx        = (int*)(ws + CIDX_OFF);
  int*   ncc         = (int*)(ws + NCC_OFF);

  preproc_kernel<<<PB_N, 192, 0, stream>>>(
      image_token_features, patches_i8, sp,
      concept_text_features, concepts_i8, scq,
      image_features, imgn, text_features, txtn,
      concept_counts, Maxbuf, cidx, ncc);

  rc_gemm_max_kernel<<<NBLK, 256, 0, stream>>>(patches_i8, concepts_i8, sp, scq,
                                               cidx, ncc, Maxbuf);

  loss_kernel<<<2*BATCH, 128, 0, stream>>>(imgn, txtn, Maxbuf, concept_counts,
                                           logit_scale, logit_bias, part);
  finalize_kernel<<<1, 256, 0, stream>>>(part, out);
}